// Round 2
// baseline (585.543 us; speedup 1.0000x reference)
//
#include <hip/hip_runtime.h>

// InteractionBlock (MACE-style) on MI355X — round 11.
// R10 post-mortem: grouping (G=2) did NOT cut gather FETCH (L2-miss counter;
// IF$ absorbed tpw either way) and regressed -47us via serialization. Revert.
// New analysis: VALUBusy 45% x 142us = ~244 VALU inst/edge -> the per-node
// EPILOGUE (msg@Wl0, msg@Wl1, out@Wp0/Wp1 as scalar FMA loops, ~2400
// inst/node) dominates k_gather5, not the edge loop. That is 2.46 GFLOP of
// GEMM-shaped work on the vector ALU.
// R11: split epilogue out of gather. k_gather6 = edge loop only (LDS 0,
// occupancy -> 32-wave cap), writes msgS[128]/msgV[3][192] per node. New
// k_post MFMA-izes all four GEMMs with the established hi/lo-bf16 exact
// trick (3 MFMAs per product), fusing the atomic-species elementwise mix
// in C-fragment layout with an LDS transpose between GEMM stages.

typedef unsigned short u16;
typedef unsigned int u32;
typedef __attribute__((ext_vector_type(8))) short bf16x8;
typedef __attribute__((ext_vector_type(4))) float f32x4;

#define CW_UP0 0
#define CW_UP1 4096
#define CW_M1  8192
#define CW_M2  8704
#define CW_M3  12800
#define CW_M4  16896
#define CW_L0  37376
#define CW_L1  45568
#define CW_P0  57856
#define CW_P1  61952
#define CW_S01 66048
#define CW_S02 66688
#define CW_S03 67968
#define CW_S11 69248
#define CW_S12 69888
#define CW_S13 70528
#define CW_TOTAL 71808

#define C_SILU     1.6765224f
#define INV_SQRT3  0.57735027f
#define INV_SQRT2  0.70710678f
#define SC_L1      0.35355339f
#define SC_L234    0.125f

#define HS16 72             // u16 per h-row (64 + pad 8): rows 144B, 16B-aligned
#define NFRAG 116           // 60 MLP frags + 16 Wl0 + 24 Wl1 + 8 Wp0 + 8 Wp1
#define FW0 60
#define FW1 76
#define FP0 100
#define FP1 108

__device__ __forceinline__ float b2f(u16 u) {
  union { u32 i; float f; } x; x.i = ((u32)u) << 16; return x.f;
}
__device__ __forceinline__ u16 f2b(float f) {
  union { float f; u32 i; } x; x.f = f;
  u32 i = x.i;
  u32 r = (i + 0x7fffu + ((i >> 16) & 1u)) >> 16;
  return (u16)r;
}
__device__ __forceinline__ float ldf(const void* p, size_t i, int f32) {
  return f32 ? ((const float*)p)[i] : b2f(((const u16*)p)[i]);
}
__device__ __forceinline__ float silu_n(float x) {
  return C_SILU * x / (1.0f + __expf(-x));
}

// ---- dtype detector
__global__ void k_detect(const void* nf, int* flag) {
  __shared__ int cnt;
  if (threadIdx.x == 0) cnt = 0;
  __syncthreads();
  const u16* p = (const u16*)nf;
  int wild = 0;
  for (int i = threadIdx.x; i < 4096; i += 256) {
    float ax = fabsf(b2f(p[i]));
    if (!(ax <= 1e10f) || (ax != 0.f && ax < 1e-10f)) wild++;
  }
  atomicAdd(&cnt, wild);
  __syncthreads();
  if (threadIdx.x == 0) *flag = (cnt > 100) ? 1 : 0;
}

struct WPtrs { const void* p[16]; };

// ---- front mega-kernel: prep | prepB | hist | node_up
__global__ __launch_bounds__(256) void k_front(
    WPtrs wp, float* __restrict__ cw, u16* __restrict__ bwH,
    u16* __restrict__ bwL, const int* __restrict__ je, int* __restrict__ deg,
    const void* __restrict__ nf, float* __restrict__ sup,
    float* __restrict__ vup, int nN, int nE, int nb0,
    const int* __restrict__ flagp) {
  __shared__ float row[4][256];
  const int f32 = *flagp;
  int bid = blockIdx.x, tid = threadIdx.x;

  if (bid < 281) {                      // ---- prep: cw table
    const int   sizes[16]  = {4096,4096,512,4096,4096,20480,8192,12288,4096,
                              4096,640,1280,1280,640,640,1280};
    const float scales[16] = {0.125f,0.125f,0.35355339f,0.125f,0.125f,0.125f,
                              0.08838835f,0.07216878f,0.125f,0.125f,
                              1.f,1.f,1.f,1.f,1.f,1.f};
    int gid = bid * 256 + tid;
    if (gid >= CW_TOTAL) return;
    int off = gid, seg = 0;
    while (off >= sizes[seg]) { off -= sizes[seg]; seg++; }
    cw[gid] = ldf(wp.p[seg], off, f32) * scales[seg];
  } else if (bid < 513) {               // ---- prepB: MFMA B-fragments hi/lo
    int gid = (bid - 281) * 256 + tid;  // < 59392 exactly (116 frags)
    int f = gid >> 9, idx = gid & 511;
    int l = idx >> 3, j = idx & 7;
    int q = l >> 4, col16 = l & 15;
    float v = 0.f;
    if (f < 4) {                        // Wm1: K=8 (padded to 32), N=64
      int k = q * 8 + j, n = f * 16 + col16;
      if (k < 8) v = ldf(wp.p[2], (size_t)k * 64 + n, f32);
    } else if (f < 20) {                // Wm2/Wm3: K=64, N=64
      const void* w = (f < 12) ? wp.p[3] : wp.p[4];
      int t = (f < 12) ? f - 4 : f - 12;
      int n = (t >> 1) * 16 + col16, ks = t & 1;
      int k = ks * 32 + q * 8 + j;
      v = ldf(w, (size_t)k * 64 + n, f32);
    } else if (f < 60) {                // Wm4: K=64, N=320
      int t = f - 20;
      int n = (t >> 1) * 16 + col16, ks = t & 1;
      int k = ks * 32 + q * 8 + j;
      v = ldf(wp.p[5], (size_t)k * 320 + n, f32);
    } else if (f < 76) {                // Wl0: K=128, N=64, scaled
      int t = f - FW0, ks = t >> 2, n = t & 3;
      int k = ks * 32 + q * 8 + j;
      v = ldf(wp.p[6], (size_t)k * 64 + n * 16 + col16, f32) * 0.08838835f;
    } else if (f < 100) {               // Wl1: K=192, N=64, scaled
      int t = f - FW1, ks = t >> 2, n = t & 3;
      int k = ks * 32 + q * 8 + j;
      v = ldf(wp.p[7], (size_t)k * 64 + n * 16 + col16, f32) * 0.07216878f;
    } else if (f < 108) {               // Wp0: K=64, N=64, scaled
      int t = f - FP0, ks = t >> 2, n = t & 3;
      int k = ks * 32 + q * 8 + j;
      v = ldf(wp.p[8], (size_t)k * 64 + n * 16 + col16, f32) * 0.125f;
    } else {                            // Wp1: K=64, N=64, scaled
      int t = f - FP1, ks = t >> 2, n = t & 3;
      int k = ks * 32 + q * 8 + j;
      v = ldf(wp.p[9], (size_t)k * 64 + n * 16 + col16, f32) * 0.125f;
    }
    u16 hi = f2b(v);
    u16 lo = f2b(v - b2f(hi));
    size_t o = (size_t)f * 512 + (size_t)l * 8 + j;
    bwH[o] = hi;
    bwL[o] = lo;
  } else if (bid < nb0) {               // ---- hist
    int e = (bid - 513) * 256 + tid;
    if (e < nE) atomicAdd(&deg[je[e]], 1);
  } else {                              // ---- node_up (raw weights)
    int w = tid >> 6, l = tid & 63;
    int n = (bid - nb0) * 4 + w;
    bool valid = n < nN;
    int nn = valid ? n : 0;
#pragma unroll
    for (int t = 0; t < 4; t++)
      row[w][t * 64 + l] = ldf(nf, (size_t)nn * 256 + t * 64 + l, f32);
    __syncthreads();
    float sacc = 0.f, v0 = 0.f, v1 = 0.f, v2 = 0.f;
#pragma unroll 8
    for (int c = 0; c < 64; c++) {
      float w0 = ldf(wp.p[0], (size_t)c * 64 + l, f32);
      float w1 = ldf(wp.p[1], (size_t)c * 64 + l, f32);
      sacc += row[w][c] * w0;
      v0 += row[w][64 + c * 3 + 0] * w1;
      v1 += row[w][64 + c * 3 + 1] * w1;
      v2 += row[w][64 + c * 3 + 2] * w1;
    }
    if (valid) {
      sup[(size_t)n * 64 + l] = sacc * 0.125f;
      vup[((size_t)n * 3 + 0) * 64 + l] = v0 * 0.125f;
      vup[((size_t)n * 3 + 1) * 64 + l] = v1 * 0.125f;
      vup[((size_t)n * 3 + 2) * 64 + l] = v2 * 0.125f;
    }
  }
}

// ---- CSR scan
__global__ __launch_bounds__(256) void k_scan(const int* __restrict__ deg,
                                              int* __restrict__ offs,
                                              int* __restrict__ cursor, int nN) {
  __shared__ int part[256];
  int t = threadIdx.x;
  int per = (nN + 255) / 256;
  int lo = t * per, hi = (t + 1) * per; if (hi > nN) hi = nN;
  int s = 0;
  for (int i = lo; i < hi; i++) s += deg[i];
  part[t] = s;
  __syncthreads();
  if (t == 0) {
    int run = 0;
    for (int i = 0; i < 256; i++) { int v = part[i]; part[i] = run; run += v; }
    offs[nN] = run;
  }
  __syncthreads();
  int run = part[t];
  for (int i = lo; i < hi; i++) {
    offs[i] = run; cursor[i] = run; run += deg[i];
  }
}

// ---- scatter2: CSR slot fill + pre-gather of ie/ea/ef into slot order (fp32)
__global__ __launch_bounds__(256) void k_scatter2(
    const int* __restrict__ je, const int* __restrict__ ie,
    const void* __restrict__ ea, const void* __restrict__ ef,
    int* __restrict__ cursor, int* __restrict__ iSlot,
    float4* __restrict__ eaSlot, float4* __restrict__ efSlot, int nE,
    const int* __restrict__ flagp) {
  const int f32 = *flagp;
  int e = blockIdx.x * 256 + threadIdx.x;
  if (e >= nE) return;
  int pos = atomicAdd(&cursor[je[e]], 1);
  iSlot[pos] = ie[e];
  float4 av;
  float4 f0, f1;
  if (f32) {
    av = ((const float4*)ea)[e];
    f0 = ((const float4*)ef)[(size_t)e * 2];
    f1 = ((const float4*)ef)[(size_t)e * 2 + 1];
  } else {
    uint2 r = ((const uint2*)ea)[e];
    av = make_float4(b2f(r.x & 0xffff), b2f(r.x >> 16),
                     b2f(r.y & 0xffff), b2f(r.y >> 16));
    uint4 u = ((const uint4*)ef)[e];
    f0 = make_float4(b2f(u.x & 0xffff), b2f(u.x >> 16),
                     b2f(u.y & 0xffff), b2f(u.y >> 16));
    f1 = make_float4(b2f(u.z & 0xffff), b2f(u.z >> 16),
                     b2f(u.w & 0xffff), b2f(u.w >> 16));
  }
  eaSlot[pos] = av;
  efSlot[(size_t)pos * 2] = f0;
  efSlot[(size_t)pos * 2 + 1] = f1;
}

// ---- MFMA edge MLP v4: one wave = 64 slots; bf16 activations in LDS (u16);
// weights hi/lo exact; L1 inputs hi/lo from fp32 efSlot.
__global__ __launch_bounds__(192) void k_mlp4(
    const float4* __restrict__ efSlot, const int* __restrict__ offs,
    const u16* __restrict__ bwH, const u16* __restrict__ bwL,
    u16* __restrict__ tpw, int gn0, int gn1, int capEff) {
  __shared__ u16 H[3][64 * HS16];
  int tid = threadIdx.x;
  int w = tid >> 6, l = tid & 63;
  int m = l & 15, q = l >> 4;
  int base = offs[gn0];
  int cnt = offs[gn1] - base;
  int lim = cnt < capEff ? cnt : capEff;
  int tb = (blockIdx.x * 3 + w) * 64;
  if (tb >= lim) return;
  u16* Hw = H[w];

  bf16x8 zero8 = {0,0,0,0,0,0,0,0};
  bf16x8 A1h[4], A1l[4];
#pragma unroll
  for (int t = 0; t < 4; t++) { A1h[t] = zero8; A1l[t] = zero8; }
  if (q == 0) {
#pragma unroll
    for (int t = 0; t < 4; t++) {
      int s = tb + t * 16 + m; if (s > lim - 1) s = lim - 1;
      // efSlot holds ABSOLUTE slot indices — add the group base.
      float4 q0 = efSlot[((size_t)(base + s)) * 2];
      float4 q1 = efSlot[((size_t)(base + s)) * 2 + 1];
      float v[8] = {q0.x, q0.y, q0.z, q0.w, q1.x, q1.y, q1.z, q1.w};
      bf16x8 hi, lo;
#pragma unroll
      for (int j = 0; j < 8; j++) {
        u16 h = f2b(v[j]);
        hi[j] = (short)h;
        lo[j] = (short)f2b(v[j] - b2f(h));
      }
      A1h[t] = hi; A1l[t] = lo;
    }
  }
  // L1: 3 MFMAs per (n,t)
#pragma unroll
  for (int n = 0; n < 4; n++) {
    bf16x8 Bh = *(const bf16x8*)(bwH + (size_t)n * 512 + (size_t)l * 8);
    bf16x8 Bl = *(const bf16x8*)(bwL + (size_t)n * 512 + (size_t)l * 8);
#pragma unroll
    for (int t = 0; t < 4; t++) {
      f32x4 c = (f32x4){0.f, 0.f, 0.f, 0.f};
      c = __builtin_amdgcn_mfma_f32_16x16x32_bf16(A1h[t], Bh, c, 0, 0, 0);
      c = __builtin_amdgcn_mfma_f32_16x16x32_bf16(A1l[t], Bh, c, 0, 0, 0);
      c = __builtin_amdgcn_mfma_f32_16x16x32_bf16(A1h[t], Bl, c, 0, 0, 0);
#pragma unroll
      for (int r = 0; r < 4; r++)
        Hw[(t * 16 + q * 4 + r) * HS16 + n * 16 + m] =
            f2b(silu_n(c[r] * SC_L1));
    }
  }

  // L2, L3: 4 MFMAs per (n,t): Ah*B{0,1}{h,l}
#pragma unroll
  for (int layer = 0; layer < 2; layer++) {
    int fragBase = 4 + layer * 8;
    bf16x8 Ah[2][4];
#pragma unroll
    for (int ks = 0; ks < 2; ks++)
#pragma unroll
      for (int t = 0; t < 4; t++)
        Ah[ks][t] = *(const bf16x8*)(Hw + (t * 16 + m) * HS16 + ks * 32 + q * 8);
#pragma unroll
    for (int n = 0; n < 4; n++) {
      bf16x8 B0h = *(const bf16x8*)(bwH + (size_t)(fragBase + n * 2 + 0) * 512 +
                                    (size_t)l * 8);
      bf16x8 B0l = *(const bf16x8*)(bwL + (size_t)(fragBase + n * 2 + 0) * 512 +
                                    (size_t)l * 8);
      bf16x8 B1h = *(const bf16x8*)(bwH + (size_t)(fragBase + n * 2 + 1) * 512 +
                                    (size_t)l * 8);
      bf16x8 B1l = *(const bf16x8*)(bwL + (size_t)(fragBase + n * 2 + 1) * 512 +
                                    (size_t)l * 8);
#pragma unroll
      for (int t = 0; t < 4; t++) {
        f32x4 c = (f32x4){0.f, 0.f, 0.f, 0.f};
        c = __builtin_amdgcn_mfma_f32_16x16x32_bf16(Ah[0][t], B0h, c, 0, 0, 0);
        c = __builtin_amdgcn_mfma_f32_16x16x32_bf16(Ah[0][t], B0l, c, 0, 0, 0);
        c = __builtin_amdgcn_mfma_f32_16x16x32_bf16(Ah[1][t], B1h, c, 0, 0, 0);
        c = __builtin_amdgcn_mfma_f32_16x16x32_bf16(Ah[1][t], B1l, c, 0, 0, 0);
#pragma unroll
        for (int r = 0; r < 4; r++)
          Hw[(t * 16 + q * 4 + r) * HS16 + n * 16 + m] =
              f2b(silu_n(c[r] * SC_L234));
      }
    }
  }

  // L4: 64 -> 320; store bf16 tpw[slot][320]
  {
    bf16x8 Ah[2][4];
#pragma unroll
    for (int ks = 0; ks < 2; ks++)
#pragma unroll
      for (int t = 0; t < 4; t++)
        Ah[ks][t] = *(const bf16x8*)(Hw + (t * 16 + m) * HS16 + ks * 32 + q * 8);
    for (int n = 0; n < 20; n++) {
      bf16x8 B0h = *(const bf16x8*)(bwH + (size_t)(20 + n * 2 + 0) * 512 +
                                    (size_t)l * 8);
      bf16x8 B0l = *(const bf16x8*)(bwL + (size_t)(20 + n * 2 + 0) * 512 +
                                    (size_t)l * 8);
      bf16x8 B1h = *(const bf16x8*)(bwH + (size_t)(20 + n * 2 + 1) * 512 +
                                    (size_t)l * 8);
      bf16x8 B1l = *(const bf16x8*)(bwL + (size_t)(20 + n * 2 + 1) * 512 +
                                    (size_t)l * 8);
#pragma unroll
      for (int t = 0; t < 4; t++) {
        f32x4 c = (f32x4){0.f, 0.f, 0.f, 0.f};
        c = __builtin_amdgcn_mfma_f32_16x16x32_bf16(Ah[0][t], B0h, c, 0, 0, 0);
        c = __builtin_amdgcn_mfma_f32_16x16x32_bf16(Ah[0][t], B0l, c, 0, 0, 0);
        c = __builtin_amdgcn_mfma_f32_16x16x32_bf16(Ah[1][t], B1h, c, 0, 0, 0);
        c = __builtin_amdgcn_mfma_f32_16x16x32_bf16(Ah[1][t], B1l, c, 0, 0, 0);
#pragma unroll
        for (int r = 0; r < 4; r++) {
          int srow = tb + t * 16 + q * 4 + r;
          if (srow < lim)
            tpw[(size_t)srow * 320 + n * 16 + m] = f2b(c[r] * SC_L234);
        }
      }
    }
  }
}

// ---- gather v6: edge loop ONLY (epilogue moved to k_post). One wave per
// node; no LDS -> occupancy at the 32-wave cap. Writes msgS/msgV.
__global__ __launch_bounds__(256) void k_gather6(
    const int* __restrict__ iSlot, const float4* __restrict__ eaSlot,
    const int* __restrict__ offs, const float* __restrict__ sup,
    const float* __restrict__ vup, const u16* __restrict__ tpw,
    float* __restrict__ msgS, float* __restrict__ msgV,
    int gn0, int gn1, int capEff) {
  int w = threadIdx.x >> 6, l = threadIdx.x & 63;
  int n = gn0 + blockIdx.x * 4 + w;
  if (n >= gn1) return;
  int gbase = offs[gn0];
  int start = offs[n];
  int deg = offs[n + 1] - start;
  int avail = capEff - (start - gbase);
  int dmax = deg < avail ? deg : avail;
  if (dmax < 0) dmax = 0;

  float as0 = 0.f, as1 = 0.f;
  float av[9];
#pragma unroll
  for (int m = 0; m < 9; m++) av[m] = 0.f;

  for (int c0 = 0; c0 < dmax; c0 += 64) {
    int rem = dmax - c0;
    int cend = rem < 64 ? rem : 64;
    int iA = 0;
    float4 eaA = make_float4(0.f, 0.f, 0.f, 0.f);
    if (l < cend) {
      iA = iSlot[start + c0 + l];
      eaA = eaSlot[start + c0 + l];
    }
    for (int qq = 0; qq < cend; qq++) {
      int i = __shfl(iA, qq);
      float eas = __shfl(eaA.x, qq);
      float ev0 = __shfl(eaA.y, qq);
      float ev1 = __shfl(eaA.z, qq);
      float ev2 = __shfl(eaA.w, qq);
      const u16* tp = tpw + (size_t)(start - gbase + c0 + qq) * 320;
      float wa  = b2f(tp[l]);
      float wbv = b2f(tp[64 + l]);
      float wc  = b2f(tp[128 + l]);
      float wd  = b2f(tp[192 + l]);
      float we_ = b2f(tp[256 + l]);
      float xs  = sup[(size_t)i * 64 + l];
      float xv0 = vup[((size_t)i * 3 + 0) * 64 + l];
      float xv1 = vup[((size_t)i * 3 + 1) * 64 + l];
      float xv2 = vup[((size_t)i * 3 + 2) * 64 + l];
      float dot = xv0 * ev0 + xv1 * ev1 + xv2 * ev2;
      as0 += wa * xs * eas;
      as1 += wbv * dot * INV_SQRT3;
      float wcxs = wc * xs;
      float wde  = wd * eas;
      float wef  = we_ * INV_SQRT2;
      av[0] += wcxs * ev0; av[1] += wcxs * ev1; av[2] += wcxs * ev2;
      av[3] += wde * xv0;  av[4] += wde * xv1;  av[5] += wde * xv2;
      av[6] += wef * (xv1 * ev2 - xv2 * ev1);
      av[7] += wef * (xv2 * ev0 - xv0 * ev2);
      av[8] += wef * (xv0 * ev1 - xv1 * ev0);
    }
  }

  msgS[(size_t)n * 128 + l] = as0;
  msgS[(size_t)n * 128 + 64 + l] = as1;
#pragma unroll
  for (int c = 0; c < 3; c++) {
    msgV[(size_t)n * 576 + c * 192 + l]       = av[c];
    msgV[(size_t)n * 576 + c * 192 + 64 + l]  = av[3 + c];
    msgV[(size_t)n * 576 + c * 192 + 128 + l] = av[6 + c];
  }
}

// ---- post: MFMA epilogue. One block per 64-node tile; wave w owns output
// cols w*16..w*16+15. GEMM1 (msgS@Wl0, msgV@Wl1 x3) -> elementwise species
// mix in C-fragment layout -> LDS transpose -> GEMM2 (@Wp0, @Wp1 x3).
// All products hi/lo-bf16 exact (3 MFMAs).
#define POST_G2(SRC, FB, STORE_S, COMP)                                        \
  {                                                                            \
    __syncthreads();                                                           \
    _Pragma("unroll")                                                          \
    for (int t = 0; t < 4; t++)                                                \
      _Pragma("unroll")                                                        \
      for (int r = 0; r < 4; r++)                                              \
        T[t * 16 + q * 4 + r][w * 16 + m] = SRC[t][r];                         \
    __syncthreads();                                                           \
    f32x4 d[4];                                                                \
    _Pragma("unroll")                                                          \
    for (int t = 0; t < 4; t++) d[t] = (f32x4){0.f, 0.f, 0.f, 0.f};            \
    _Pragma("unroll")                                                          \
    for (int ks = 0; ks < 2; ks++) {                                           \
      bf16x8 Bh = *(const bf16x8*)(bwH + (size_t)(FB + ks * 4 + w) * 512 +     \
                                   (size_t)l * 8);                             \
      bf16x8 Bl = *(const bf16x8*)(bwL + (size_t)(FB + ks * 4 + w) * 512 +     \
                                   (size_t)l * 8);                             \
      _Pragma("unroll")                                                        \
      for (int t = 0; t < 4; t++) {                                            \
        bf16x8 Ah, Al;                                                         \
        _Pragma("unroll")                                                      \
        for (int j = 0; j < 8; j++) {                                          \
          float vx = T[t * 16 + m][ks * 32 + q * 8 + j];                       \
          u16 h = f2b(vx);                                                     \
          Ah[j] = (short)h;                                                    \
          Al[j] = (short)f2b(vx - b2f(h));                                     \
        }                                                                      \
        d[t] = __builtin_amdgcn_mfma_f32_16x16x32_bf16(Ah, Bh, d[t], 0, 0, 0); \
        d[t] = __builtin_amdgcn_mfma_f32_16x16x32_bf16(Al, Bh, d[t], 0, 0, 0); \
        d[t] = __builtin_amdgcn_mfma_f32_16x16x32_bf16(Ah, Bl, d[t], 0, 0, 0); \
      }                                                                        \
    }                                                                          \
    _Pragma("unroll")                                                          \
    for (int t = 0; t < 4; t++)                                                \
      _Pragma("unroll")                                                        \
      for (int r = 0; r < 4; r++) {                                            \
        int node = n0 + t * 16 + q * 4 + r;                                    \
        if (node < nN) {                                                       \
          int ch = w * 16 + m;                                                 \
          size_t basep = (size_t)node * 256;                                   \
          size_t oidx = STORE_S ? (basep + ch) : (basep + 64 + ch * 3 + COMP); \
          if (f32) ((float*)out)[oidx] = d[t][r];                              \
          else ((u16*)out)[oidx] = f2b(d[t][r]);                               \
        }                                                                      \
      }                                                                        \
  }

__global__ __launch_bounds__(256) void k_post(
    const float* __restrict__ msgS, const float* __restrict__ msgV,
    const int* __restrict__ an, const float* __restrict__ cw,
    const u16* __restrict__ bwH, const u16* __restrict__ bwL,
    void* __restrict__ out, int nN, const int* __restrict__ flagp) {
  __shared__ float T[64][69];
  const int f32 = *flagp;
  int tid = threadIdx.x;
  int w = tid >> 6, l = tid & 63;
  int m = l & 15, q = l >> 4;
  int n0 = blockIdx.x * 64;

  // ---- GEMM1-s: s2 = msgS[64x128] @ Wl0'  (K=128)
  f32x4 s2[4];
#pragma unroll
  for (int t = 0; t < 4; t++) s2[t] = (f32x4){0.f, 0.f, 0.f, 0.f};
#pragma unroll
  for (int ks = 0; ks < 4; ks++) {
    bf16x8 Bh = *(const bf16x8*)(bwH + (size_t)(FW0 + ks * 4 + w) * 512 +
                                 (size_t)l * 8);
    bf16x8 Bl = *(const bf16x8*)(bwL + (size_t)(FW0 + ks * 4 + w) * 512 +
                                 (size_t)l * 8);
#pragma unroll
    for (int t = 0; t < 4; t++) {
      int row = n0 + t * 16 + m; if (row > nN - 1) row = nN - 1;
      const float* ap = msgS + (size_t)row * 128 + ks * 32 + q * 8;
      bf16x8 Ah, Al;
#pragma unroll
      for (int j = 0; j < 8; j++) {
        float vx = ap[j];
        u16 h = f2b(vx);
        Ah[j] = (short)h;
        Al[j] = (short)f2b(vx - b2f(h));
      }
      s2[t] = __builtin_amdgcn_mfma_f32_16x16x32_bf16(Ah, Bh, s2[t], 0, 0, 0);
      s2[t] = __builtin_amdgcn_mfma_f32_16x16x32_bf16(Al, Bh, s2[t], 0, 0, 0);
      s2[t] = __builtin_amdgcn_mfma_f32_16x16x32_bf16(Ah, Bl, s2[t], 0, 0, 0);
    }
  }

  // ---- GEMM1-v: v2_c = msgV[.,c,192] @ Wl1'  (K=192, 3 comps)
  f32x4 v2[3][4];
#pragma unroll
  for (int c = 0; c < 3; c++)
#pragma unroll
    for (int t = 0; t < 4; t++) v2[c][t] = (f32x4){0.f, 0.f, 0.f, 0.f};
#pragma unroll
  for (int ks = 0; ks < 6; ks++) {
    bf16x8 Bh = *(const bf16x8*)(bwH + (size_t)(FW1 + ks * 4 + w) * 512 +
                                 (size_t)l * 8);
    bf16x8 Bl = *(const bf16x8*)(bwL + (size_t)(FW1 + ks * 4 + w) * 512 +
                                 (size_t)l * 8);
#pragma unroll
    for (int c = 0; c < 3; c++)
#pragma unroll
      for (int t = 0; t < 4; t++) {
        int row = n0 + t * 16 + m; if (row > nN - 1) row = nN - 1;
        const float* ap = msgV + (size_t)row * 576 + c * 192 + ks * 32 + q * 8;
        bf16x8 Ah, Al;
#pragma unroll
        for (int j = 0; j < 8; j++) {
          float vx = ap[j];
          u16 h = f2b(vx);
          Ah[j] = (short)h;
          Al[j] = (short)f2b(vx - b2f(h));
        }
        v2[c][t] = __builtin_amdgcn_mfma_f32_16x16x32_bf16(Ah, Bh, v2[c][t], 0, 0, 0);
        v2[c][t] = __builtin_amdgcn_mfma_f32_16x16x32_bf16(Al, Bh, v2[c][t], 0, 0, 0);
        v2[c][t] = __builtin_amdgcn_mfma_f32_16x16x32_bf16(Ah, Bl, v2[c][t], 0, 0, 0);
      }
  }

  // ---- elementwise species mix (C-fragment layout: row=t*16+q*4+r, col=w*16+m)
  f32x4 os[4];
  f32x4 ov[3][4];
#pragma unroll
  for (int t = 0; t < 4; t++) {
#pragma unroll
    for (int r = 0; r < 4; r++) {
      int node = n0 + t * 16 + q * 4 + r;
      int nc = node > nN - 1 ? nN - 1 : node;
      int a = an[nc];
      int ch = w * 16 + m;
      float s2v = s2[t][r];
      float va = v2[0][t][r], vb = v2[1][t][r], vc = v2[2][t][r];
      float vv = va * va + vb * vb + vc * vc;
      float w01  = cw[CW_S01 + a * 64 + ch];
      float w02a = cw[CW_S02 + a * 128 + ch];
      float w02b = cw[CW_S02 + a * 128 + 64 + ch];
      float w03a = cw[CW_S03 + a * 128 + ch];
      float w03b = cw[CW_S03 + a * 128 + 64 + ch];
      float w11  = cw[CW_S11 + a * 64 + ch];
      float w12  = cw[CW_S12 + a * 64 + ch];
      float w13a = cw[CW_S13 + a * 128 + ch];
      float w13b = cw[CW_S13 + a * 128 + 64 + ch];
      float s2sq = s2v * s2v;
      float vvs = vv * INV_SQRT3;
      float outs = w01 * s2v + w02a * s2sq + w02b * vvs + w03a * s2sq * s2v +
                   w03b * s2v * vvs;
      float coef = w11 + w12 * s2v + w13a * s2sq + w13b * vvs;
      os[t][r] = outs;
      ov[0][t][r] = coef * va;
      ov[1][t][r] = coef * vb;
      ov[2][t][r] = coef * vc;
    }
  }

  // ---- GEMM2 + store (4 matrices, sequential through LDS transpose)
  POST_G2(os, FP0, 1, 0)
  POST_G2(ov[0], FP1, 0, 0)
  POST_G2(ov[1], FP1, 0, 1)
  POST_G2(ov[2], FP1, 0, 2)
}

extern "C" void kernel_launch(void* const* d_in, const int* in_sizes, int n_in,
                              void* d_out, int out_size, void* d_ws,
                              size_t ws_size, hipStream_t stream) {
  const void* nf = d_in[0];
  const void* ef = d_in[1];
  const void* ea = d_in[2];
  const int* ie = (const int*)d_in[3];
  const int* je = (const int*)d_in[4];
  const int* an = (const int*)d_in[5];
  int nN = in_sizes[0] / 256;   // 20000
  int nE = in_sizes[3];         // 320000

  size_t intCnt = (size_t)3 * nN + 1 + nE;     // deg, offs, cursor, iSlot
  intCnt = (intCnt + 3) & ~(size_t)3;
  int* deg    = (int*)d_ws;
  int* offs   = deg + nN;
  int* cursor = offs + nN + 1;
  int* iSlot  = cursor + nN;
  float* cw   = (float*)d_ws + intCnt;
  float* sup  = cw + CW_TOTAL;
  float* vup  = sup + (size_t)nN * 64;
  int* flag   = (int*)(vup + (size_t)nN * 192);
  float* msgS = (float*)(flag + 1);
  float* msgV = msgS + (size_t)nN * 128;

  size_t eaByte = (size_t)((char*)(msgV + (size_t)nN * 576) - (char*)d_ws);
  eaByte = (eaByte + 15) & ~(size_t)15;
  float4* eaSlot = (float4*)((char*)d_ws + eaByte);
  float4* efSlot = eaSlot + nE;                 // nE float4 x2 for ef
  size_t bwByte = eaByte + (size_t)nE * 16 + (size_t)nE * 32;
  u16* bwH = (u16*)((char*)d_ws + bwByte);
  u16* bwL = bwH + (size_t)NFRAG * 512;
  size_t tpwByte = bwByte + (size_t)NFRAG * 512 * 2 * 2;
  tpwByte = (tpwByte + 15) & ~(size_t)15;
  u16* tpw = (u16*)((char*)d_ws + tpwByte);
  size_t capE = (ws_size > tpwByte) ? (ws_size - tpwByte) / 640 : 0;

  // G policy: smallest g whose worst-case per-group slot count fits tpw
  // workspace (G=1 preferred; grouping is only a workspace-overflow fallback).
  int G = 64;
  int nodesPer = (nN + 63) / 64;
  for (int g = 1; g <= 64; g++) {
    int npg = (nN + g - 1) / g;
    size_t worst = (size_t)npg * nE / nN + 6000;
    if (worst <= capE) { G = g; nodesPer = npg; break; }
  }
  int capEff = (int)((size_t)nodesPer * nE / nN + 6000);
  if ((size_t)capEff > capE) capEff = (int)capE;

  k_detect<<<1, 256, 0, stream>>>(nf, flag);
  hipMemsetAsync(deg, 0, (size_t)nN * sizeof(int), stream);

  WPtrs wp;
  const int widx[16] = {6, 7, 8, 9, 10, 11, 12, 13, 20, 21,
                        14, 15, 16, 17, 18, 19};
  for (int i = 0; i < 16; i++) wp.p[i] = d_in[widx[i]];

  int histNB = (nE + 255) / 256;
  int nb0 = 513 + histNB;
  int nupNB = (nN + 3) / 4;
  k_front<<<nb0 + nupNB, 256, 0, stream>>>(wp, cw, bwH, bwL, je, deg, nf,
                                           sup, vup, nN, nE, nb0, flag);
  k_scan<<<1, 256, 0, stream>>>(deg, offs, cursor, nN);
  k_scatter2<<<(nE + 255) / 256, 256, 0, stream>>>(je, ie, ea, ef, cursor,
                                                   iSlot, eaSlot, efSlot, nE,
                                                   flag);

  for (int g = 0; g < G; g++) {
    int gn0 = g * nodesPer;
    if (gn0 >= nN) break;
    int gn1 = gn0 + nodesPer; if (gn1 > nN) gn1 = nN;
    int mlpBlocks = (capEff + 191) / 192;
    k_mlp4<<<mlpBlocks, 192, 0, stream>>>(efSlot, offs, bwH, bwL, tpw,
                                          gn0, gn1, capEff);
    int gBlocks = (gn1 - gn0 + 3) / 4;
    k_gather6<<<gBlocks, 256, 0, stream>>>(iSlot, eaSlot, offs, sup, vup,
                                           tpw, msgS, msgV, gn0, gn1, capEff);
  }
  int postNB = (nN + 63) / 64;
  k_post<<<postNB, 256, 0, stream>>>(msgS, msgV, an, cw, bwH, bwL, d_out,
                                     nN, flag);
}

// Round 3
// 508.909 us; speedup vs baseline: 1.1506x; 1.1506x over previous
//
#include <hip/hip_runtime.h>

// InteractionBlock (MACE-style) on MI355X — round 12.
// R11 post-mortem: k_post (64-node tiles, 313 blocks) = 121us at 7% occupancy
// (1.2 blocks/CU) + per-MFMA fragment rebuild from fp32 (8 scalar loads +
// ~50 VALU f2b per triple) + 801k LDS bank conflicts. Latency-bound.
// R12: (a) 16-node tiles -> 1250 blocks (~20 waves/CU); (b) k_gather6 stores
// msg as hi/lo bf16 PLANES (same bytes) so k_post2 A-fragments are direct
// 16B bf16x8 loads, no conversion VALU; (c) GEMM2 LDS transpose in u16
// hi/lo planes (convert on write, vector-load on read), row pad 88 u16.

typedef unsigned short u16;
typedef unsigned int u32;
typedef __attribute__((ext_vector_type(8))) short bf16x8;
typedef __attribute__((ext_vector_type(4))) float f32x4;

#define CW_UP0 0
#define CW_UP1 4096
#define CW_M1  8192
#define CW_M2  8704
#define CW_M3  12800
#define CW_M4  16896
#define CW_L0  37376
#define CW_L1  45568
#define CW_P0  57856
#define CW_P1  61952
#define CW_S01 66048
#define CW_S02 66688
#define CW_S03 67968
#define CW_S11 69248
#define CW_S12 69888
#define CW_S13 70528
#define CW_TOTAL 71808

#define C_SILU     1.6765224f
#define INV_SQRT3  0.57735027f
#define INV_SQRT2  0.70710678f
#define SC_L1      0.35355339f
#define SC_L234    0.125f

#define HS16 72             // u16 per h-row (64 + pad 8): rows 144B, 16B-aligned
#define NFRAG 116           // 60 MLP frags + 16 Wl0 + 24 Wl1 + 8 Wp0 + 8 Wp1
#define FW0 60
#define FW1 76
#define FP0 100
#define FP1 108
#define TP 88               // k_post2 LDS transpose row pad (u16)

__device__ __forceinline__ float b2f(u16 u) {
  union { u32 i; float f; } x; x.i = ((u32)u) << 16; return x.f;
}
__device__ __forceinline__ u16 f2b(float f) {
  union { float f; u32 i; } x; x.f = f;
  u32 i = x.i;
  u32 r = (i + 0x7fffu + ((i >> 16) & 1u)) >> 16;
  return (u16)r;
}
__device__ __forceinline__ float ldf(const void* p, size_t i, int f32) {
  return f32 ? ((const float*)p)[i] : b2f(((const u16*)p)[i]);
}
__device__ __forceinline__ float silu_n(float x) {
  return C_SILU * x / (1.0f + __expf(-x));
}

// ---- dtype detector
__global__ void k_detect(const void* nf, int* flag) {
  __shared__ int cnt;
  if (threadIdx.x == 0) cnt = 0;
  __syncthreads();
  const u16* p = (const u16*)nf;
  int wild = 0;
  for (int i = threadIdx.x; i < 4096; i += 256) {
    float ax = fabsf(b2f(p[i]));
    if (!(ax <= 1e10f) || (ax != 0.f && ax < 1e-10f)) wild++;
  }
  atomicAdd(&cnt, wild);
  __syncthreads();
  if (threadIdx.x == 0) *flag = (cnt > 100) ? 1 : 0;
}

struct WPtrs { const void* p[16]; };

// ---- front mega-kernel: prep | prepB | hist | node_up
__global__ __launch_bounds__(256) void k_front(
    WPtrs wp, float* __restrict__ cw, u16* __restrict__ bwH,
    u16* __restrict__ bwL, const int* __restrict__ je, int* __restrict__ deg,
    const void* __restrict__ nf, float* __restrict__ sup,
    float* __restrict__ vup, int nN, int nE, int nb0,
    const int* __restrict__ flagp) {
  __shared__ float row[4][256];
  const int f32 = *flagp;
  int bid = blockIdx.x, tid = threadIdx.x;

  if (bid < 281) {                      // ---- prep: cw table
    const int   sizes[16]  = {4096,4096,512,4096,4096,20480,8192,12288,4096,
                              4096,640,1280,1280,640,640,1280};
    const float scales[16] = {0.125f,0.125f,0.35355339f,0.125f,0.125f,0.125f,
                              0.08838835f,0.07216878f,0.125f,0.125f,
                              1.f,1.f,1.f,1.f,1.f,1.f};
    int gid = bid * 256 + tid;
    if (gid >= CW_TOTAL) return;
    int off = gid, seg = 0;
    while (off >= sizes[seg]) { off -= sizes[seg]; seg++; }
    cw[gid] = ldf(wp.p[seg], off, f32) * scales[seg];
  } else if (bid < 513) {               // ---- prepB: MFMA B-fragments hi/lo
    int gid = (bid - 281) * 256 + tid;  // < 59392 exactly (116 frags)
    int f = gid >> 9, idx = gid & 511;
    int l = idx >> 3, j = idx & 7;
    int q = l >> 4, col16 = l & 15;
    float v = 0.f;
    if (f < 4) {                        // Wm1: K=8 (padded to 32), N=64
      int k = q * 8 + j, n = f * 16 + col16;
      if (k < 8) v = ldf(wp.p[2], (size_t)k * 64 + n, f32);
    } else if (f < 20) {                // Wm2/Wm3: K=64, N=64
      const void* w = (f < 12) ? wp.p[3] : wp.p[4];
      int t = (f < 12) ? f - 4 : f - 12;
      int n = (t >> 1) * 16 + col16, ks = t & 1;
      int k = ks * 32 + q * 8 + j;
      v = ldf(w, (size_t)k * 64 + n, f32);
    } else if (f < 60) {                // Wm4: K=64, N=320
      int t = f - 20;
      int n = (t >> 1) * 16 + col16, ks = t & 1;
      int k = ks * 32 + q * 8 + j;
      v = ldf(wp.p[5], (size_t)k * 320 + n, f32);
    } else if (f < 76) {                // Wl0: K=128, N=64, scaled
      int t = f - FW0, ks = t >> 2, n = t & 3;
      int k = ks * 32 + q * 8 + j;
      v = ldf(wp.p[6], (size_t)k * 64 + n * 16 + col16, f32) * 0.08838835f;
    } else if (f < 100) {               // Wl1: K=192, N=64, scaled
      int t = f - FW1, ks = t >> 2, n = t & 3;
      int k = ks * 32 + q * 8 + j;
      v = ldf(wp.p[7], (size_t)k * 64 + n * 16 + col16, f32) * 0.07216878f;
    } else if (f < 108) {               // Wp0: K=64, N=64, scaled
      int t = f - FP0, ks = t >> 2, n = t & 3;
      int k = ks * 32 + q * 8 + j;
      v = ldf(wp.p[8], (size_t)k * 64 + n * 16 + col16, f32) * 0.125f;
    } else {                            // Wp1: K=64, N=64, scaled
      int t = f - FP1, ks = t >> 2, n = t & 3;
      int k = ks * 32 + q * 8 + j;
      v = ldf(wp.p[9], (size_t)k * 64 + n * 16 + col16, f32) * 0.125f;
    }
    u16 hi = f2b(v);
    u16 lo = f2b(v - b2f(hi));
    size_t o = (size_t)f * 512 + (size_t)l * 8 + j;
    bwH[o] = hi;
    bwL[o] = lo;
  } else if (bid < nb0) {               // ---- hist
    int e = (bid - 513) * 256 + tid;
    if (e < nE) atomicAdd(&deg[je[e]], 1);
  } else {                              // ---- node_up (raw weights)
    int w = tid >> 6, l = tid & 63;
    int n = (bid - nb0) * 4 + w;
    bool valid = n < nN;
    int nn = valid ? n : 0;
#pragma unroll
    for (int t = 0; t < 4; t++)
      row[w][t * 64 + l] = ldf(nf, (size_t)nn * 256 + t * 64 + l, f32);
    __syncthreads();
    float sacc = 0.f, v0 = 0.f, v1 = 0.f, v2 = 0.f;
#pragma unroll 8
    for (int c = 0; c < 64; c++) {
      float w0 = ldf(wp.p[0], (size_t)c * 64 + l, f32);
      float w1 = ldf(wp.p[1], (size_t)c * 64 + l, f32);
      sacc += row[w][c] * w0;
      v0 += row[w][64 + c * 3 + 0] * w1;
      v1 += row[w][64 + c * 3 + 1] * w1;
      v2 += row[w][64 + c * 3 + 2] * w1;
    }
    if (valid) {
      sup[(size_t)n * 64 + l] = sacc * 0.125f;
      vup[((size_t)n * 3 + 0) * 64 + l] = v0 * 0.125f;
      vup[((size_t)n * 3 + 1) * 64 + l] = v1 * 0.125f;
      vup[((size_t)n * 3 + 2) * 64 + l] = v2 * 0.125f;
    }
  }
}

// ---- CSR scan
__global__ __launch_bounds__(256) void k_scan(const int* __restrict__ deg,
                                              int* __restrict__ offs,
                                              int* __restrict__ cursor, int nN) {
  __shared__ int part[256];
  int t = threadIdx.x;
  int per = (nN + 255) / 256;
  int lo = t * per, hi = (t + 1) * per; if (hi > nN) hi = nN;
  int s = 0;
  for (int i = lo; i < hi; i++) s += deg[i];
  part[t] = s;
  __syncthreads();
  if (t == 0) {
    int run = 0;
    for (int i = 0; i < 256; i++) { int v = part[i]; part[i] = run; run += v; }
    offs[nN] = run;
  }
  __syncthreads();
  int run = part[t];
  for (int i = lo; i < hi; i++) {
    offs[i] = run; cursor[i] = run; run += deg[i];
  }
}

// ---- scatter2: CSR slot fill + pre-gather of ie/ea/ef into slot order (fp32)
__global__ __launch_bounds__(256) void k_scatter2(
    const int* __restrict__ je, const int* __restrict__ ie,
    const void* __restrict__ ea, const void* __restrict__ ef,
    int* __restrict__ cursor, int* __restrict__ iSlot,
    float4* __restrict__ eaSlot, float4* __restrict__ efSlot, int nE,
    const int* __restrict__ flagp) {
  const int f32 = *flagp;
  int e = blockIdx.x * 256 + threadIdx.x;
  if (e >= nE) return;
  int pos = atomicAdd(&cursor[je[e]], 1);
  iSlot[pos] = ie[e];
  float4 av;
  float4 f0, f1;
  if (f32) {
    av = ((const float4*)ea)[e];
    f0 = ((const float4*)ef)[(size_t)e * 2];
    f1 = ((const float4*)ef)[(size_t)e * 2 + 1];
  } else {
    uint2 r = ((const uint2*)ea)[e];
    av = make_float4(b2f(r.x & 0xffff), b2f(r.x >> 16),
                     b2f(r.y & 0xffff), b2f(r.y >> 16));
    uint4 u = ((const uint4*)ef)[e];
    f0 = make_float4(b2f(u.x & 0xffff), b2f(u.x >> 16),
                     b2f(u.y & 0xffff), b2f(u.y >> 16));
    f1 = make_float4(b2f(u.z & 0xffff), b2f(u.z >> 16),
                     b2f(u.w & 0xffff), b2f(u.w >> 16));
  }
  eaSlot[pos] = av;
  efSlot[(size_t)pos * 2] = f0;
  efSlot[(size_t)pos * 2 + 1] = f1;
}

// ---- MFMA edge MLP v4: one wave = 64 slots; bf16 activations in LDS (u16);
// weights hi/lo exact; L1 inputs hi/lo from fp32 efSlot.
__global__ __launch_bounds__(192) void k_mlp4(
    const float4* __restrict__ efSlot, const int* __restrict__ offs,
    const u16* __restrict__ bwH, const u16* __restrict__ bwL,
    u16* __restrict__ tpw, int gn0, int gn1, int capEff) {
  __shared__ u16 H[3][64 * HS16];
  int tid = threadIdx.x;
  int w = tid >> 6, l = tid & 63;
  int m = l & 15, q = l >> 4;
  int base = offs[gn0];
  int cnt = offs[gn1] - base;
  int lim = cnt < capEff ? cnt : capEff;
  int tb = (blockIdx.x * 3 + w) * 64;
  if (tb >= lim) return;
  u16* Hw = H[w];

  bf16x8 zero8 = {0,0,0,0,0,0,0,0};
  bf16x8 A1h[4], A1l[4];
#pragma unroll
  for (int t = 0; t < 4; t++) { A1h[t] = zero8; A1l[t] = zero8; }
  if (q == 0) {
#pragma unroll
    for (int t = 0; t < 4; t++) {
      int s = tb + t * 16 + m; if (s > lim - 1) s = lim - 1;
      // efSlot holds ABSOLUTE slot indices — add the group base.
      float4 q0 = efSlot[((size_t)(base + s)) * 2];
      float4 q1 = efSlot[((size_t)(base + s)) * 2 + 1];
      float v[8] = {q0.x, q0.y, q0.z, q0.w, q1.x, q1.y, q1.z, q1.w};
      bf16x8 hi, lo;
#pragma unroll
      for (int j = 0; j < 8; j++) {
        u16 h = f2b(v[j]);
        hi[j] = (short)h;
        lo[j] = (short)f2b(v[j] - b2f(h));
      }
      A1h[t] = hi; A1l[t] = lo;
    }
  }
  // L1: 3 MFMAs per (n,t)
#pragma unroll
  for (int n = 0; n < 4; n++) {
    bf16x8 Bh = *(const bf16x8*)(bwH + (size_t)n * 512 + (size_t)l * 8);
    bf16x8 Bl = *(const bf16x8*)(bwL + (size_t)n * 512 + (size_t)l * 8);
#pragma unroll
    for (int t = 0; t < 4; t++) {
      f32x4 c = (f32x4){0.f, 0.f, 0.f, 0.f};
      c = __builtin_amdgcn_mfma_f32_16x16x32_bf16(A1h[t], Bh, c, 0, 0, 0);
      c = __builtin_amdgcn_mfma_f32_16x16x32_bf16(A1l[t], Bh, c, 0, 0, 0);
      c = __builtin_amdgcn_mfma_f32_16x16x32_bf16(A1h[t], Bl, c, 0, 0, 0);
#pragma unroll
      for (int r = 0; r < 4; r++)
        Hw[(t * 16 + q * 4 + r) * HS16 + n * 16 + m] =
            f2b(silu_n(c[r] * SC_L1));
    }
  }

  // L2, L3: 4 MFMAs per (n,t): Ah*B{0,1}{h,l}
#pragma unroll
  for (int layer = 0; layer < 2; layer++) {
    int fragBase = 4 + layer * 8;
    bf16x8 Ah[2][4];
#pragma unroll
    for (int ks = 0; ks < 2; ks++)
#pragma unroll
      for (int t = 0; t < 4; t++)
        Ah[ks][t] = *(const bf16x8*)(Hw + (t * 16 + m) * HS16 + ks * 32 + q * 8);
#pragma unroll
    for (int n = 0; n < 4; n++) {
      bf16x8 B0h = *(const bf16x8*)(bwH + (size_t)(fragBase + n * 2 + 0) * 512 +
                                    (size_t)l * 8);
      bf16x8 B0l = *(const bf16x8*)(bwL + (size_t)(fragBase + n * 2 + 0) * 512 +
                                    (size_t)l * 8);
      bf16x8 B1h = *(const bf16x8*)(bwH + (size_t)(fragBase + n * 2 + 1) * 512 +
                                    (size_t)l * 8);
      bf16x8 B1l = *(const bf16x8*)(bwL + (size_t)(fragBase + n * 2 + 1) * 512 +
                                    (size_t)l * 8);
#pragma unroll
      for (int t = 0; t < 4; t++) {
        f32x4 c = (f32x4){0.f, 0.f, 0.f, 0.f};
        c = __builtin_amdgcn_mfma_f32_16x16x32_bf16(Ah[0][t], B0h, c, 0, 0, 0);
        c = __builtin_amdgcn_mfma_f32_16x16x32_bf16(Ah[0][t], B0l, c, 0, 0, 0);
        c = __builtin_amdgcn_mfma_f32_16x16x32_bf16(Ah[1][t], B1h, c, 0, 0, 0);
        c = __builtin_amdgcn_mfma_f32_16x16x32_bf16(Ah[1][t], B1l, c, 0, 0, 0);
#pragma unroll
        for (int r = 0; r < 4; r++)
          Hw[(t * 16 + q * 4 + r) * HS16 + n * 16 + m] =
              f2b(silu_n(c[r] * SC_L234));
      }
    }
  }

  // L4: 64 -> 320; store bf16 tpw[slot][320]
  {
    bf16x8 Ah[2][4];
#pragma unroll
    for (int ks = 0; ks < 2; ks++)
#pragma unroll
      for (int t = 0; t < 4; t++)
        Ah[ks][t] = *(const bf16x8*)(Hw + (t * 16 + m) * HS16 + ks * 32 + q * 8);
    for (int n = 0; n < 20; n++) {
      bf16x8 B0h = *(const bf16x8*)(bwH + (size_t)(20 + n * 2 + 0) * 512 +
                                    (size_t)l * 8);
      bf16x8 B0l = *(const bf16x8*)(bwL + (size_t)(20 + n * 2 + 0) * 512 +
                                    (size_t)l * 8);
      bf16x8 B1h = *(const bf16x8*)(bwH + (size_t)(20 + n * 2 + 1) * 512 +
                                    (size_t)l * 8);
      bf16x8 B1l = *(const bf16x8*)(bwL + (size_t)(20 + n * 2 + 1) * 512 +
                                    (size_t)l * 8);
#pragma unroll
      for (int t = 0; t < 4; t++) {
        f32x4 c = (f32x4){0.f, 0.f, 0.f, 0.f};
        c = __builtin_amdgcn_mfma_f32_16x16x32_bf16(Ah[0][t], B0h, c, 0, 0, 0);
        c = __builtin_amdgcn_mfma_f32_16x16x32_bf16(Ah[0][t], B0l, c, 0, 0, 0);
        c = __builtin_amdgcn_mfma_f32_16x16x32_bf16(Ah[1][t], B1h, c, 0, 0, 0);
        c = __builtin_amdgcn_mfma_f32_16x16x32_bf16(Ah[1][t], B1l, c, 0, 0, 0);
#pragma unroll
        for (int r = 0; r < 4; r++) {
          int srow = tb + t * 16 + q * 4 + r;
          if (srow < lim)
            tpw[(size_t)srow * 320 + n * 16 + m] = f2b(c[r] * SC_L234);
        }
      }
    }
  }
}

// ---- gather v6b: edge loop only; stores msg as hi/lo bf16 planes so k_post2
// A-fragments are direct 16B vector loads.
__global__ __launch_bounds__(256) void k_gather6(
    const int* __restrict__ iSlot, const float4* __restrict__ eaSlot,
    const int* __restrict__ offs, const float* __restrict__ sup,
    const float* __restrict__ vup, const u16* __restrict__ tpw,
    u16* __restrict__ msgSh, u16* __restrict__ msgSl,
    u16* __restrict__ msgVh, u16* __restrict__ msgVl,
    int gn0, int gn1, int capEff) {
  int w = threadIdx.x >> 6, l = threadIdx.x & 63;
  int n = gn0 + blockIdx.x * 4 + w;
  if (n >= gn1) return;
  int gbase = offs[gn0];
  int start = offs[n];
  int deg = offs[n + 1] - start;
  int avail = capEff - (start - gbase);
  int dmax = deg < avail ? deg : avail;
  if (dmax < 0) dmax = 0;

  float as0 = 0.f, as1 = 0.f;
  float av[9];
#pragma unroll
  for (int m = 0; m < 9; m++) av[m] = 0.f;

  for (int c0 = 0; c0 < dmax; c0 += 64) {
    int rem = dmax - c0;
    int cend = rem < 64 ? rem : 64;
    int iA = 0;
    float4 eaA = make_float4(0.f, 0.f, 0.f, 0.f);
    if (l < cend) {
      iA = iSlot[start + c0 + l];
      eaA = eaSlot[start + c0 + l];
    }
    for (int qq = 0; qq < cend; qq++) {
      int i = __shfl(iA, qq);
      float eas = __shfl(eaA.x, qq);
      float ev0 = __shfl(eaA.y, qq);
      float ev1 = __shfl(eaA.z, qq);
      float ev2 = __shfl(eaA.w, qq);
      const u16* tp = tpw + (size_t)(start - gbase + c0 + qq) * 320;
      float wa  = b2f(tp[l]);
      float wbv = b2f(tp[64 + l]);
      float wc  = b2f(tp[128 + l]);
      float wd  = b2f(tp[192 + l]);
      float we_ = b2f(tp[256 + l]);
      float xs  = sup[(size_t)i * 64 + l];
      float xv0 = vup[((size_t)i * 3 + 0) * 64 + l];
      float xv1 = vup[((size_t)i * 3 + 1) * 64 + l];
      float xv2 = vup[((size_t)i * 3 + 2) * 64 + l];
      float dot = xv0 * ev0 + xv1 * ev1 + xv2 * ev2;
      as0 += wa * xs * eas;
      as1 += wbv * dot * INV_SQRT3;
      float wcxs = wc * xs;
      float wde  = wd * eas;
      float wef  = we_ * INV_SQRT2;
      av[0] += wcxs * ev0; av[1] += wcxs * ev1; av[2] += wcxs * ev2;
      av[3] += wde * xv0;  av[4] += wde * xv1;  av[5] += wde * xv2;
      av[6] += wef * (xv1 * ev2 - xv2 * ev1);
      av[7] += wef * (xv2 * ev0 - xv0 * ev2);
      av[8] += wef * (xv0 * ev1 - xv1 * ev0);
    }
  }

  // store hi/lo bf16 planes
  {
    u16 h0 = f2b(as0), h1 = f2b(as1);
    msgSh[(size_t)n * 128 + l] = h0;
    msgSh[(size_t)n * 128 + 64 + l] = h1;
    msgSl[(size_t)n * 128 + l] = f2b(as0 - b2f(h0));
    msgSl[(size_t)n * 128 + 64 + l] = f2b(as1 - b2f(h1));
  }
#pragma unroll
  for (int c = 0; c < 3; c++) {
#pragma unroll
    for (int b = 0; b < 3; b++) {
      float x = av[b * 3 + c];
      u16 h = f2b(x);
      size_t o = (size_t)n * 576 + c * 192 + b * 64 + l;
      msgVh[o] = h;
      msgVl[o] = f2b(x - b2f(h));
    }
  }
}

// ---- post v2: 16-node tiles (1250 blocks), wave w owns cols w*16..+15.
// A-fragments are direct bf16x8 loads from msg planes; GEMM2 transpose via
// u16 hi/lo LDS planes (convert on write side only).
__global__ __launch_bounds__(256) void k_post2(
    const u16* __restrict__ msgSh, const u16* __restrict__ msgSl,
    const u16* __restrict__ msgVh, const u16* __restrict__ msgVl,
    const int* __restrict__ an, const float* __restrict__ cw,
    const u16* __restrict__ bwH, const u16* __restrict__ bwL,
    void* __restrict__ out, int nN, const int* __restrict__ flagp) {
  __shared__ u16 Thi[16][TP];
  __shared__ u16 Tlo[16][TP];
  const int f32 = *flagp;
  int tid = threadIdx.x;
  int w = tid >> 6, l = tid & 63;
  int m = l & 15, q = l >> 4;
  int n0 = blockIdx.x * 16;
  int rowA = n0 + m; if (rowA > nN - 1) rowA = nN - 1;

  // ---- GEMM1-s: s2 = msgS[16x128] @ Wl0frag(w)   (K=128)
  f32x4 s2 = (f32x4){0.f, 0.f, 0.f, 0.f};
#pragma unroll
  for (int ks = 0; ks < 4; ks++) {
    bf16x8 Bh = *(const bf16x8*)(bwH + (size_t)(FW0 + ks * 4 + w) * 512 +
                                 (size_t)l * 8);
    bf16x8 Bl = *(const bf16x8*)(bwL + (size_t)(FW0 + ks * 4 + w) * 512 +
                                 (size_t)l * 8);
    bf16x8 Ah = *(const bf16x8*)(msgSh + (size_t)rowA * 128 + ks * 32 + q * 8);
    bf16x8 Al = *(const bf16x8*)(msgSl + (size_t)rowA * 128 + ks * 32 + q * 8);
    s2 = __builtin_amdgcn_mfma_f32_16x16x32_bf16(Ah, Bh, s2, 0, 0, 0);
    s2 = __builtin_amdgcn_mfma_f32_16x16x32_bf16(Al, Bh, s2, 0, 0, 0);
    s2 = __builtin_amdgcn_mfma_f32_16x16x32_bf16(Ah, Bl, s2, 0, 0, 0);
  }

  // ---- GEMM1-v: v2_c = msgV[.,c,192] @ Wl1frag(w)   (K=192, 3 comps)
  f32x4 v2[3];
#pragma unroll
  for (int c = 0; c < 3; c++) v2[c] = (f32x4){0.f, 0.f, 0.f, 0.f};
#pragma unroll
  for (int ks = 0; ks < 6; ks++) {
    bf16x8 Bh = *(const bf16x8*)(bwH + (size_t)(FW1 + ks * 4 + w) * 512 +
                                 (size_t)l * 8);
    bf16x8 Bl = *(const bf16x8*)(bwL + (size_t)(FW1 + ks * 4 + w) * 512 +
                                 (size_t)l * 8);
#pragma unroll
    for (int c = 0; c < 3; c++) {
      size_t o = (size_t)rowA * 576 + c * 192 + ks * 32 + q * 8;
      bf16x8 Ah = *(const bf16x8*)(msgVh + o);
      bf16x8 Al = *(const bf16x8*)(msgVl + o);
      v2[c] = __builtin_amdgcn_mfma_f32_16x16x32_bf16(Ah, Bh, v2[c], 0, 0, 0);
      v2[c] = __builtin_amdgcn_mfma_f32_16x16x32_bf16(Al, Bh, v2[c], 0, 0, 0);
      v2[c] = __builtin_amdgcn_mfma_f32_16x16x32_bf16(Ah, Bl, v2[c], 0, 0, 0);
    }
  }

  // ---- elementwise species mix (C-frag layout: row=q*4+r, col=w*16+m)
  float os[4], ov0[4], ov1[4], ov2[4];
#pragma unroll
  for (int r = 0; r < 4; r++) {
    int node = n0 + q * 4 + r;
    int nc = node > nN - 1 ? nN - 1 : node;
    int a = an[nc];
    int ch = w * 16 + m;
    float s2v = s2[r];
    float va = v2[0][r], vb = v2[1][r], vc = v2[2][r];
    float vv = va * va + vb * vb + vc * vc;
    float w01  = cw[CW_S01 + a * 64 + ch];
    float w02a = cw[CW_S02 + a * 128 + ch];
    float w02b = cw[CW_S02 + a * 128 + 64 + ch];
    float w03a = cw[CW_S03 + a * 128 + ch];
    float w03b = cw[CW_S03 + a * 128 + 64 + ch];
    float w11  = cw[CW_S11 + a * 64 + ch];
    float w12  = cw[CW_S12 + a * 64 + ch];
    float w13a = cw[CW_S13 + a * 128 + ch];
    float w13b = cw[CW_S13 + a * 128 + 64 + ch];
    float s2sq = s2v * s2v;
    float vvs = vv * INV_SQRT3;
    os[r] = w01 * s2v + w02a * s2sq + w02b * vvs + w03a * s2sq * s2v +
            w03b * s2v * vvs;
    float coef = w11 + w12 * s2v + w13a * s2sq + w13b * vvs;
    ov0[r] = coef * va;
    ov1[r] = coef * vb;
    ov2[r] = coef * vc;
  }

  // ---- GEMM2 x4 through u16 hi/lo LDS transpose
#define POST2_G2(SRC, FB, STORE_S, COMP)                                       \
  {                                                                            \
    __syncthreads();                                                           \
    _Pragma("unroll")                                                          \
    for (int r = 0; r < 4; r++) {                                              \
      float x = SRC[r];                                                        \
      u16 h = f2b(x);                                                          \
      Thi[q * 4 + r][w * 16 + m] = h;                                          \
      Tlo[q * 4 + r][w * 16 + m] = f2b(x - b2f(h));                            \
    }                                                                          \
    __syncthreads();                                                           \
    f32x4 d = (f32x4){0.f, 0.f, 0.f, 0.f};                                     \
    _Pragma("unroll")                                                          \
    for (int ks = 0; ks < 2; ks++) {                                           \
      bf16x8 Bh = *(const bf16x8*)(bwH + (size_t)(FB + ks * 4 + w) * 512 +     \
                                   (size_t)l * 8);                             \
      bf16x8 Bl = *(const bf16x8*)(bwL + (size_t)(FB + ks * 4 + w) * 512 +     \
                                   (size_t)l * 8);                             \
      bf16x8 Ah = *(const bf16x8*)(&Thi[m][ks * 32 + q * 8]);                  \
      bf16x8 Al = *(const bf16x8*)(&Tlo[m][ks * 32 + q * 8]);                  \
      d = __builtin_amdgcn_mfma_f32_16x16x32_bf16(Ah, Bh, d, 0, 0, 0);         \
      d = __builtin_amdgcn_mfma_f32_16x16x32_bf16(Al, Bh, d, 0, 0, 0);         \
      d = __builtin_amdgcn_mfma_f32_16x16x32_bf16(Ah, Bl, d, 0, 0, 0);         \
    }                                                                          \
    _Pragma("unroll")                                                          \
    for (int r = 0; r < 4; r++) {                                              \
      int node = n0 + q * 4 + r;                                               \
      if (node < nN) {                                                         \
        int ch = w * 16 + m;                                                   \
        size_t basep = (size_t)node * 256;                                     \
        size_t oidx = STORE_S ? (basep + ch) : (basep + 64 + ch * 3 + COMP);   \
        if (f32) ((float*)out)[oidx] = d[r];                                   \
        else ((u16*)out)[oidx] = f2b(d[r]);                                    \
      }                                                                        \
    }                                                                          \
  }

  POST2_G2(os, FP0, 1, 0)
  POST2_G2(ov0, FP1, 0, 0)
  POST2_G2(ov1, FP1, 0, 1)
  POST2_G2(ov2, FP1, 0, 2)
#undef POST2_G2
}

extern "C" void kernel_launch(void* const* d_in, const int* in_sizes, int n_in,
                              void* d_out, int out_size, void* d_ws,
                              size_t ws_size, hipStream_t stream) {
  const void* nf = d_in[0];
  const void* ef = d_in[1];
  const void* ea = d_in[2];
  const int* ie = (const int*)d_in[3];
  const int* je = (const int*)d_in[4];
  const int* an = (const int*)d_in[5];
  int nN = in_sizes[0] / 256;   // 20000
  int nE = in_sizes[3];         // 320000

  size_t intCnt = (size_t)3 * nN + 1 + nE;     // deg, offs, cursor, iSlot
  intCnt = (intCnt + 3) & ~(size_t)3;
  int* deg    = (int*)d_ws;
  int* offs   = deg + nN;
  int* cursor = offs + nN + 1;
  int* iSlot  = cursor + nN;
  float* cw   = (float*)d_ws + intCnt;
  float* sup  = cw + CW_TOTAL;
  float* vup  = sup + (size_t)nN * 64;
  int* flag   = (int*)(vup + (size_t)nN * 192);

  size_t msgByte = (size_t)((char*)(flag + 1) - (char*)d_ws);
  msgByte = (msgByte + 15) & ~(size_t)15;
  u16* msgSh = (u16*)((char*)d_ws + msgByte);
  u16* msgSl = msgSh + (size_t)nN * 128;
  u16* msgVh = msgSl + (size_t)nN * 128;
  u16* msgVl = msgVh + (size_t)nN * 576;

  size_t eaByte = msgByte + (size_t)nN * 1408 * 2;
  eaByte = (eaByte + 15) & ~(size_t)15;
  float4* eaSlot = (float4*)((char*)d_ws + eaByte);
  float4* efSlot = eaSlot + nE;                 // nE float4 x2 for ef
  size_t bwByte = eaByte + (size_t)nE * 16 + (size_t)nE * 32;
  u16* bwH = (u16*)((char*)d_ws + bwByte);
  u16* bwL = bwH + (size_t)NFRAG * 512;
  size_t tpwByte = bwByte + (size_t)NFRAG * 512 * 2 * 2;
  tpwByte = (tpwByte + 15) & ~(size_t)15;
  u16* tpw = (u16*)((char*)d_ws + tpwByte);
  size_t capE = (ws_size > tpwByte) ? (ws_size - tpwByte) / 640 : 0;

  // G policy: smallest g whose worst-case per-group slot count fits tpw
  // workspace (G=1 preferred).
  int G = 64;
  int nodesPer = (nN + 63) / 64;
  for (int g = 1; g <= 64; g++) {
    int npg = (nN + g - 1) / g;
    size_t worst = (size_t)npg * nE / nN + 6000;
    if (worst <= capE) { G = g; nodesPer = npg; break; }
  }
  int capEff = (int)((size_t)nodesPer * nE / nN + 6000);
  if ((size_t)capEff > capE) capEff = (int)capE;

  k_detect<<<1, 256, 0, stream>>>(nf, flag);
  hipMemsetAsync(deg, 0, (size_t)nN * sizeof(int), stream);

  WPtrs wp;
  const int widx[16] = {6, 7, 8, 9, 10, 11, 12, 13, 20, 21,
                        14, 15, 16, 17, 18, 19};
  for (int i = 0; i < 16; i++) wp.p[i] = d_in[widx[i]];

  int histNB = (nE + 255) / 256;
  int nb0 = 513 + histNB;
  int nupNB = (nN + 3) / 4;
  k_front<<<nb0 + nupNB, 256, 0, stream>>>(wp, cw, bwH, bwL, je, deg, nf,
                                           sup, vup, nN, nE, nb0, flag);
  k_scan<<<1, 256, 0, stream>>>(deg, offs, cursor, nN);
  k_scatter2<<<(nE + 255) / 256, 256, 0, stream>>>(je, ie, ea, ef, cursor,
                                                   iSlot, eaSlot, efSlot, nE,
                                                   flag);

  for (int g = 0; g < G; g++) {
    int gn0 = g * nodesPer;
    if (gn0 >= nN) break;
    int gn1 = gn0 + nodesPer; if (gn1 > nN) gn1 = nN;
    int mlpBlocks = (capEff + 191) / 192;
    k_mlp4<<<mlpBlocks, 192, 0, stream>>>(efSlot, offs, bwH, bwL, tpw,
                                          gn0, gn1, capEff);
    int gBlocks = (gn1 - gn0 + 3) / 4;
    k_gather6<<<gBlocks, 256, 0, stream>>>(iSlot, eaSlot, offs, sup, vup,
                                           tpw, msgSh, msgSl, msgVh, msgVl,
                                           gn0, gn1, capEff);
  }
  int postNB = (nN + 15) / 16;
  k_post2<<<postNB, 256, 0, stream>>>(msgSh, msgSl, msgVh, msgVl, an, cw,
                                      bwH, bwL, d_out, nN, flag);
}

// Round 4
// 500.200 us; speedup vs baseline: 1.1706x; 1.0174x over previous
//
#include <hip/hip_runtime.h>

// InteractionBlock (MACE-style) on MI355X — round 13.
// R12 post-mortem: k_post2 fixed (gone from top-5). k_mlp4 = 118us with NO
// saturated pipe (Mfma 6.7%, VALU 21%, HBM 21%): issue-bound on the L4
// store scatter — 320 scalar global_store_short per lane, 4x32B partial-line
// segments per instr, realized write BW 1.64 TB/s.
// R13: L4 stores via LDS staging. After L4 A-frags are in registers, Hw is
// dead -> reuse as 64x64 u16 staging tile; compute 20 n-tiles in 5 chunks of
// 4, f2b->ds_write (cheap), then 8 coalesced dwordx4 stores per chunk
// (128B-contiguous row segments). 320 -> 40 store instrs/wave, full lines.

typedef unsigned short u16;
typedef unsigned int u32;
typedef __attribute__((ext_vector_type(8))) short bf16x8;
typedef __attribute__((ext_vector_type(4))) float f32x4;

#define CW_UP0 0
#define CW_UP1 4096
#define CW_M1  8192
#define CW_M2  8704
#define CW_M3  12800
#define CW_M4  16896
#define CW_L0  37376
#define CW_L1  45568
#define CW_P0  57856
#define CW_P1  61952
#define CW_S01 66048
#define CW_S02 66688
#define CW_S03 67968
#define CW_S11 69248
#define CW_S12 69888
#define CW_S13 70528
#define CW_TOTAL 71808

#define C_SILU     1.6765224f
#define INV_SQRT3  0.57735027f
#define INV_SQRT2  0.70710678f
#define SC_L1      0.35355339f
#define SC_L234    0.125f

#define HS16 72             // u16 per h-row (64 + pad 8): rows 144B, 16B-aligned
#define NFRAG 116           // 60 MLP frags + 16 Wl0 + 24 Wl1 + 8 Wp0 + 8 Wp1
#define FW0 60
#define FW1 76
#define FP0 100
#define FP1 108
#define TP 88               // k_post2 LDS transpose row pad (u16)

__device__ __forceinline__ float b2f(u16 u) {
  union { u32 i; float f; } x; x.i = ((u32)u) << 16; return x.f;
}
__device__ __forceinline__ u16 f2b(float f) {
  union { float f; u32 i; } x; x.f = f;
  u32 i = x.i;
  u32 r = (i + 0x7fffu + ((i >> 16) & 1u)) >> 16;
  return (u16)r;
}
__device__ __forceinline__ float ldf(const void* p, size_t i, int f32) {
  return f32 ? ((const float*)p)[i] : b2f(((const u16*)p)[i]);
}
__device__ __forceinline__ float silu_n(float x) {
  return C_SILU * x / (1.0f + __expf(-x));
}

// ---- dtype detector
__global__ void k_detect(const void* nf, int* flag) {
  __shared__ int cnt;
  if (threadIdx.x == 0) cnt = 0;
  __syncthreads();
  const u16* p = (const u16*)nf;
  int wild = 0;
  for (int i = threadIdx.x; i < 4096; i += 256) {
    float ax = fabsf(b2f(p[i]));
    if (!(ax <= 1e10f) || (ax != 0.f && ax < 1e-10f)) wild++;
  }
  atomicAdd(&cnt, wild);
  __syncthreads();
  if (threadIdx.x == 0) *flag = (cnt > 100) ? 1 : 0;
}

struct WPtrs { const void* p[16]; };

// ---- front mega-kernel: prep | prepB | hist | node_up
__global__ __launch_bounds__(256) void k_front(
    WPtrs wp, float* __restrict__ cw, u16* __restrict__ bwH,
    u16* __restrict__ bwL, const int* __restrict__ je, int* __restrict__ deg,
    const void* __restrict__ nf, float* __restrict__ sup,
    float* __restrict__ vup, int nN, int nE, int nb0,
    const int* __restrict__ flagp) {
  __shared__ float row[4][256];
  const int f32 = *flagp;
  int bid = blockIdx.x, tid = threadIdx.x;

  if (bid < 281) {                      // ---- prep: cw table
    const int   sizes[16]  = {4096,4096,512,4096,4096,20480,8192,12288,4096,
                              4096,640,1280,1280,640,640,1280};
    const float scales[16] = {0.125f,0.125f,0.35355339f,0.125f,0.125f,0.125f,
                              0.08838835f,0.07216878f,0.125f,0.125f,
                              1.f,1.f,1.f,1.f,1.f,1.f};
    int gid = bid * 256 + tid;
    if (gid >= CW_TOTAL) return;
    int off = gid, seg = 0;
    while (off >= sizes[seg]) { off -= sizes[seg]; seg++; }
    cw[gid] = ldf(wp.p[seg], off, f32) * scales[seg];
  } else if (bid < 513) {               // ---- prepB: MFMA B-fragments hi/lo
    int gid = (bid - 281) * 256 + tid;  // < 59392 exactly (116 frags)
    int f = gid >> 9, idx = gid & 511;
    int l = idx >> 3, j = idx & 7;
    int q = l >> 4, col16 = l & 15;
    float v = 0.f;
    if (f < 4) {                        // Wm1: K=8 (padded to 32), N=64
      int k = q * 8 + j, n = f * 16 + col16;
      if (k < 8) v = ldf(wp.p[2], (size_t)k * 64 + n, f32);
    } else if (f < 20) {                // Wm2/Wm3: K=64, N=64
      const void* w = (f < 12) ? wp.p[3] : wp.p[4];
      int t = (f < 12) ? f - 4 : f - 12;
      int n = (t >> 1) * 16 + col16, ks = t & 1;
      int k = ks * 32 + q * 8 + j;
      v = ldf(w, (size_t)k * 64 + n, f32);
    } else if (f < 60) {                // Wm4: K=64, N=320
      int t = f - 20;
      int n = (t >> 1) * 16 + col16, ks = t & 1;
      int k = ks * 32 + q * 8 + j;
      v = ldf(wp.p[5], (size_t)k * 320 + n, f32);
    } else if (f < 76) {                // Wl0: K=128, N=64, scaled
      int t = f - FW0, ks = t >> 2, n = t & 3;
      int k = ks * 32 + q * 8 + j;
      v = ldf(wp.p[6], (size_t)k * 64 + n * 16 + col16, f32) * 0.08838835f;
    } else if (f < 100) {               // Wl1: K=192, N=64, scaled
      int t = f - FW1, ks = t >> 2, n = t & 3;
      int k = ks * 32 + q * 8 + j;
      v = ldf(wp.p[7], (size_t)k * 64 + n * 16 + col16, f32) * 0.07216878f;
    } else if (f < 108) {               // Wp0: K=64, N=64, scaled
      int t = f - FP0, ks = t >> 2, n = t & 3;
      int k = ks * 32 + q * 8 + j;
      v = ldf(wp.p[8], (size_t)k * 64 + n * 16 + col16, f32) * 0.125f;
    } else {                            // Wp1: K=64, N=64, scaled
      int t = f - FP1, ks = t >> 2, n = t & 3;
      int k = ks * 32 + q * 8 + j;
      v = ldf(wp.p[9], (size_t)k * 64 + n * 16 + col16, f32) * 0.125f;
    }
    u16 hi = f2b(v);
    u16 lo = f2b(v - b2f(hi));
    size_t o = (size_t)f * 512 + (size_t)l * 8 + j;
    bwH[o] = hi;
    bwL[o] = lo;
  } else if (bid < nb0) {               // ---- hist
    int e = (bid - 513) * 256 + tid;
    if (e < nE) atomicAdd(&deg[je[e]], 1);
  } else {                              // ---- node_up (raw weights)
    int w = tid >> 6, l = tid & 63;
    int n = (bid - nb0) * 4 + w;
    bool valid = n < nN;
    int nn = valid ? n : 0;
#pragma unroll
    for (int t = 0; t < 4; t++)
      row[w][t * 64 + l] = ldf(nf, (size_t)nn * 256 + t * 64 + l, f32);
    __syncthreads();
    float sacc = 0.f, v0 = 0.f, v1 = 0.f, v2 = 0.f;
#pragma unroll 8
    for (int c = 0; c < 64; c++) {
      float w0 = ldf(wp.p[0], (size_t)c * 64 + l, f32);
      float w1 = ldf(wp.p[1], (size_t)c * 64 + l, f32);
      sacc += row[w][c] * w0;
      v0 += row[w][64 + c * 3 + 0] * w1;
      v1 += row[w][64 + c * 3 + 1] * w1;
      v2 += row[w][64 + c * 3 + 2] * w1;
    }
    if (valid) {
      sup[(size_t)n * 64 + l] = sacc * 0.125f;
      vup[((size_t)n * 3 + 0) * 64 + l] = v0 * 0.125f;
      vup[((size_t)n * 3 + 1) * 64 + l] = v1 * 0.125f;
      vup[((size_t)n * 3 + 2) * 64 + l] = v2 * 0.125f;
    }
  }
}

// ---- CSR scan
__global__ __launch_bounds__(256) void k_scan(const int* __restrict__ deg,
                                              int* __restrict__ offs,
                                              int* __restrict__ cursor, int nN) {
  __shared__ int part[256];
  int t = threadIdx.x;
  int per = (nN + 255) / 256;
  int lo = t * per, hi = (t + 1) * per; if (hi > nN) hi = nN;
  int s = 0;
  for (int i = lo; i < hi; i++) s += deg[i];
  part[t] = s;
  __syncthreads();
  if (t == 0) {
    int run = 0;
    for (int i = 0; i < 256; i++) { int v = part[i]; part[i] = run; run += v; }
    offs[nN] = run;
  }
  __syncthreads();
  int run = part[t];
  for (int i = lo; i < hi; i++) {
    offs[i] = run; cursor[i] = run; run += deg[i];
  }
}

// ---- scatter2: CSR slot fill + pre-gather of ie/ea/ef into slot order (fp32)
__global__ __launch_bounds__(256) void k_scatter2(
    const int* __restrict__ je, const int* __restrict__ ie,
    const void* __restrict__ ea, const void* __restrict__ ef,
    int* __restrict__ cursor, int* __restrict__ iSlot,
    float4* __restrict__ eaSlot, float4* __restrict__ efSlot, int nE,
    const int* __restrict__ flagp) {
  const int f32 = *flagp;
  int e = blockIdx.x * 256 + threadIdx.x;
  if (e >= nE) return;
  int pos = atomicAdd(&cursor[je[e]], 1);
  iSlot[pos] = ie[e];
  float4 av;
  float4 f0, f1;
  if (f32) {
    av = ((const float4*)ea)[e];
    f0 = ((const float4*)ef)[(size_t)e * 2];
    f1 = ((const float4*)ef)[(size_t)e * 2 + 1];
  } else {
    uint2 r = ((const uint2*)ea)[e];
    av = make_float4(b2f(r.x & 0xffff), b2f(r.x >> 16),
                     b2f(r.y & 0xffff), b2f(r.y >> 16));
    uint4 u = ((const uint4*)ef)[e];
    f0 = make_float4(b2f(u.x & 0xffff), b2f(u.x >> 16),
                     b2f(u.y & 0xffff), b2f(u.y >> 16));
    f1 = make_float4(b2f(u.z & 0xffff), b2f(u.z >> 16),
                     b2f(u.w & 0xffff), b2f(u.w >> 16));
  }
  eaSlot[pos] = av;
  efSlot[(size_t)pos * 2] = f0;
  efSlot[(size_t)pos * 2 + 1] = f1;
}

// ---- MFMA edge MLP v5: one wave = 64 slots; bf16 activations in LDS (u16);
// weights hi/lo exact; L4 stores LDS-staged for full-line coalescing.
__global__ __launch_bounds__(192) void k_mlp4(
    const float4* __restrict__ efSlot, const int* __restrict__ offs,
    const u16* __restrict__ bwH, const u16* __restrict__ bwL,
    u16* __restrict__ tpw, int gn0, int gn1, int capEff) {
  __shared__ u16 H[3][64 * HS16];
  int tid = threadIdx.x;
  int w = tid >> 6, l = tid & 63;
  int m = l & 15, q = l >> 4;
  int base = offs[gn0];
  int cnt = offs[gn1] - base;
  int lim = cnt < capEff ? cnt : capEff;
  int tb = (blockIdx.x * 3 + w) * 64;
  if (tb >= lim) return;
  u16* Hw = H[w];

  bf16x8 zero8 = {0,0,0,0,0,0,0,0};
  bf16x8 A1h[4], A1l[4];
#pragma unroll
  for (int t = 0; t < 4; t++) { A1h[t] = zero8; A1l[t] = zero8; }
  if (q == 0) {
#pragma unroll
    for (int t = 0; t < 4; t++) {
      int s = tb + t * 16 + m; if (s > lim - 1) s = lim - 1;
      // efSlot holds ABSOLUTE slot indices — add the group base.
      float4 q0 = efSlot[((size_t)(base + s)) * 2];
      float4 q1 = efSlot[((size_t)(base + s)) * 2 + 1];
      float v[8] = {q0.x, q0.y, q0.z, q0.w, q1.x, q1.y, q1.z, q1.w};
      bf16x8 hi, lo;
#pragma unroll
      for (int j = 0; j < 8; j++) {
        u16 h = f2b(v[j]);
        hi[j] = (short)h;
        lo[j] = (short)f2b(v[j] - b2f(h));
      }
      A1h[t] = hi; A1l[t] = lo;
    }
  }
  // L1: 3 MFMAs per (n,t)
#pragma unroll
  for (int n = 0; n < 4; n++) {
    bf16x8 Bh = *(const bf16x8*)(bwH + (size_t)n * 512 + (size_t)l * 8);
    bf16x8 Bl = *(const bf16x8*)(bwL + (size_t)n * 512 + (size_t)l * 8);
#pragma unroll
    for (int t = 0; t < 4; t++) {
      f32x4 c = (f32x4){0.f, 0.f, 0.f, 0.f};
      c = __builtin_amdgcn_mfma_f32_16x16x32_bf16(A1h[t], Bh, c, 0, 0, 0);
      c = __builtin_amdgcn_mfma_f32_16x16x32_bf16(A1l[t], Bh, c, 0, 0, 0);
      c = __builtin_amdgcn_mfma_f32_16x16x32_bf16(A1h[t], Bl, c, 0, 0, 0);
#pragma unroll
      for (int r = 0; r < 4; r++)
        Hw[(t * 16 + q * 4 + r) * HS16 + n * 16 + m] =
            f2b(silu_n(c[r] * SC_L1));
    }
  }

  // L2, L3: 4 MFMAs per (n,t): Ah*B{0,1}{h,l}
#pragma unroll
  for (int layer = 0; layer < 2; layer++) {
    int fragBase = 4 + layer * 8;
    bf16x8 Ah[2][4];
#pragma unroll
    for (int ks = 0; ks < 2; ks++)
#pragma unroll
      for (int t = 0; t < 4; t++)
        Ah[ks][t] = *(const bf16x8*)(Hw + (t * 16 + m) * HS16 + ks * 32 + q * 8);
#pragma unroll
    for (int n = 0; n < 4; n++) {
      bf16x8 B0h = *(const bf16x8*)(bwH + (size_t)(fragBase + n * 2 + 0) * 512 +
                                    (size_t)l * 8);
      bf16x8 B0l = *(const bf16x8*)(bwL + (size_t)(fragBase + n * 2 + 0) * 512 +
                                    (size_t)l * 8);
      bf16x8 B1h = *(const bf16x8*)(bwH + (size_t)(fragBase + n * 2 + 1) * 512 +
                                    (size_t)l * 8);
      bf16x8 B1l = *(const bf16x8*)(bwL + (size_t)(fragBase + n * 2 + 1) * 512 +
                                    (size_t)l * 8);
#pragma unroll
      for (int t = 0; t < 4; t++) {
        f32x4 c = (f32x4){0.f, 0.f, 0.f, 0.f};
        c = __builtin_amdgcn_mfma_f32_16x16x32_bf16(Ah[0][t], B0h, c, 0, 0, 0);
        c = __builtin_amdgcn_mfma_f32_16x16x32_bf16(Ah[0][t], B0l, c, 0, 0, 0);
        c = __builtin_amdgcn_mfma_f32_16x16x32_bf16(Ah[1][t], B1h, c, 0, 0, 0);
        c = __builtin_amdgcn_mfma_f32_16x16x32_bf16(Ah[1][t], B1l, c, 0, 0, 0);
#pragma unroll
        for (int r = 0; r < 4; r++)
          Hw[(t * 16 + q * 4 + r) * HS16 + n * 16 + m] =
              f2b(silu_n(c[r] * SC_L234));
      }
    }
  }

  // L4: 64 -> 320 in 5 chunks of 4 n-tiles. A-frags hoisted to regs first, so
  // Hw is dead -> reuse as 64x64 u16 staging; then 8 dwordx4 coalesced stores
  // per chunk (128B-contiguous per row). Per-wave buffer: no barriers (DS is
  // in-order within a wave).
  {
    bf16x8 Ah[2][4];
#pragma unroll
    for (int ks = 0; ks < 2; ks++)
#pragma unroll
      for (int t = 0; t < 4; t++)
        Ah[ks][t] = *(const bf16x8*)(Hw + (t * 16 + m) * HS16 + ks * 32 + q * 8);
    for (int c4 = 0; c4 < 5; c4++) {
#pragma unroll
      for (int nn2 = 0; nn2 < 4; nn2++) {
        int n = c4 * 4 + nn2;
        bf16x8 B0h = *(const bf16x8*)(bwH + (size_t)(20 + n * 2 + 0) * 512 +
                                      (size_t)l * 8);
        bf16x8 B0l = *(const bf16x8*)(bwL + (size_t)(20 + n * 2 + 0) * 512 +
                                      (size_t)l * 8);
        bf16x8 B1h = *(const bf16x8*)(bwH + (size_t)(20 + n * 2 + 1) * 512 +
                                      (size_t)l * 8);
        bf16x8 B1l = *(const bf16x8*)(bwL + (size_t)(20 + n * 2 + 1) * 512 +
                                      (size_t)l * 8);
#pragma unroll
        for (int t = 0; t < 4; t++) {
          f32x4 c = (f32x4){0.f, 0.f, 0.f, 0.f};
          c = __builtin_amdgcn_mfma_f32_16x16x32_bf16(Ah[0][t], B0h, c, 0, 0, 0);
          c = __builtin_amdgcn_mfma_f32_16x16x32_bf16(Ah[0][t], B0l, c, 0, 0, 0);
          c = __builtin_amdgcn_mfma_f32_16x16x32_bf16(Ah[1][t], B1h, c, 0, 0, 0);
          c = __builtin_amdgcn_mfma_f32_16x16x32_bf16(Ah[1][t], B1l, c, 0, 0, 0);
#pragma unroll
          for (int r = 0; r < 4; r++)
            Hw[(t * 16 + q * 4 + r) * HS16 + nn2 * 16 + m] =
                f2b(c[r] * SC_L234);
        }
      }
      // coalesced copy-out: 8 iters x (8 rows x 128B)
      int r8 = l >> 3, cc = l & 7;
#pragma unroll
      for (int i = 0; i < 8; i++) {
        int row = i * 8 + r8;
        int srow = tb + row;
        if (srow < lim) {
          uint4 v = *(const uint4*)(Hw + row * HS16 + cc * 8);
          *(uint4*)(tpw + (size_t)srow * 320 + c4 * 64 + cc * 8) = v;
        }
      }
    }
  }
}

// ---- gather v6b: edge loop only; stores msg as hi/lo bf16 planes so k_post2
// A-fragments are direct 16B vector loads.
__global__ __launch_bounds__(256) void k_gather6(
    const int* __restrict__ iSlot, const float4* __restrict__ eaSlot,
    const int* __restrict__ offs, const float* __restrict__ sup,
    const float* __restrict__ vup, const u16* __restrict__ tpw,
    u16* __restrict__ msgSh, u16* __restrict__ msgSl,
    u16* __restrict__ msgVh, u16* __restrict__ msgVl,
    int gn0, int gn1, int capEff) {
  int w = threadIdx.x >> 6, l = threadIdx.x & 63;
  int n = gn0 + blockIdx.x * 4 + w;
  if (n >= gn1) return;
  int gbase = offs[gn0];
  int start = offs[n];
  int deg = offs[n + 1] - start;
  int avail = capEff - (start - gbase);
  int dmax = deg < avail ? deg : avail;
  if (dmax < 0) dmax = 0;

  float as0 = 0.f, as1 = 0.f;
  float av[9];
#pragma unroll
  for (int m = 0; m < 9; m++) av[m] = 0.f;

  for (int c0 = 0; c0 < dmax; c0 += 64) {
    int rem = dmax - c0;
    int cend = rem < 64 ? rem : 64;
    int iA = 0;
    float4 eaA = make_float4(0.f, 0.f, 0.f, 0.f);
    if (l < cend) {
      iA = iSlot[start + c0 + l];
      eaA = eaSlot[start + c0 + l];
    }
    for (int qq = 0; qq < cend; qq++) {
      int i = __shfl(iA, qq);
      float eas = __shfl(eaA.x, qq);
      float ev0 = __shfl(eaA.y, qq);
      float ev1 = __shfl(eaA.z, qq);
      float ev2 = __shfl(eaA.w, qq);
      const u16* tp = tpw + (size_t)(start - gbase + c0 + qq) * 320;
      float wa  = b2f(tp[l]);
      float wbv = b2f(tp[64 + l]);
      float wc  = b2f(tp[128 + l]);
      float wd  = b2f(tp[192 + l]);
      float we_ = b2f(tp[256 + l]);
      float xs  = sup[(size_t)i * 64 + l];
      float xv0 = vup[((size_t)i * 3 + 0) * 64 + l];
      float xv1 = vup[((size_t)i * 3 + 1) * 64 + l];
      float xv2 = vup[((size_t)i * 3 + 2) * 64 + l];
      float dot = xv0 * ev0 + xv1 * ev1 + xv2 * ev2;
      as0 += wa * xs * eas;
      as1 += wbv * dot * INV_SQRT3;
      float wcxs = wc * xs;
      float wde  = wd * eas;
      float wef  = we_ * INV_SQRT2;
      av[0] += wcxs * ev0; av[1] += wcxs * ev1; av[2] += wcxs * ev2;
      av[3] += wde * xv0;  av[4] += wde * xv1;  av[5] += wde * xv2;
      av[6] += wef * (xv1 * ev2 - xv2 * ev1);
      av[7] += wef * (xv2 * ev0 - xv0 * ev2);
      av[8] += wef * (xv0 * ev1 - xv1 * ev0);
    }
  }

  // store hi/lo bf16 planes
  {
    u16 h0 = f2b(as0), h1 = f2b(as1);
    msgSh[(size_t)n * 128 + l] = h0;
    msgSh[(size_t)n * 128 + 64 + l] = h1;
    msgSl[(size_t)n * 128 + l] = f2b(as0 - b2f(h0));
    msgSl[(size_t)n * 128 + 64 + l] = f2b(as1 - b2f(h1));
  }
#pragma unroll
  for (int c = 0; c < 3; c++) {
#pragma unroll
    for (int b = 0; b < 3; b++) {
      float x = av[b * 3 + c];
      u16 h = f2b(x);
      size_t o = (size_t)n * 576 + c * 192 + b * 64 + l;
      msgVh[o] = h;
      msgVl[o] = f2b(x - b2f(h));
    }
  }
}

// ---- post v2: 16-node tiles (1250 blocks), wave w owns cols w*16..+15.
// A-fragments are direct bf16x8 loads from msg planes; GEMM2 transpose via
// u16 hi/lo LDS planes (convert on write side only).
__global__ __launch_bounds__(256) void k_post2(
    const u16* __restrict__ msgSh, const u16* __restrict__ msgSl,
    const u16* __restrict__ msgVh, const u16* __restrict__ msgVl,
    const int* __restrict__ an, const float* __restrict__ cw,
    const u16* __restrict__ bwH, const u16* __restrict__ bwL,
    void* __restrict__ out, int nN, const int* __restrict__ flagp) {
  __shared__ u16 Thi[16][TP];
  __shared__ u16 Tlo[16][TP];
  const int f32 = *flagp;
  int tid = threadIdx.x;
  int w = tid >> 6, l = tid & 63;
  int m = l & 15, q = l >> 4;
  int n0 = blockIdx.x * 16;
  int rowA = n0 + m; if (rowA > nN - 1) rowA = nN - 1;

  // ---- GEMM1-s: s2 = msgS[16x128] @ Wl0frag(w)   (K=128)
  f32x4 s2 = (f32x4){0.f, 0.f, 0.f, 0.f};
#pragma unroll
  for (int ks = 0; ks < 4; ks++) {
    bf16x8 Bh = *(const bf16x8*)(bwH + (size_t)(FW0 + ks * 4 + w) * 512 +
                                 (size_t)l * 8);
    bf16x8 Bl = *(const bf16x8*)(bwL + (size_t)(FW0 + ks * 4 + w) * 512 +
                                 (size_t)l * 8);
    bf16x8 Ah = *(const bf16x8*)(msgSh + (size_t)rowA * 128 + ks * 32 + q * 8);
    bf16x8 Al = *(const bf16x8*)(msgSl + (size_t)rowA * 128 + ks * 32 + q * 8);
    s2 = __builtin_amdgcn_mfma_f32_16x16x32_bf16(Ah, Bh, s2, 0, 0, 0);
    s2 = __builtin_amdgcn_mfma_f32_16x16x32_bf16(Al, Bh, s2, 0, 0, 0);
    s2 = __builtin_amdgcn_mfma_f32_16x16x32_bf16(Ah, Bl, s2, 0, 0, 0);
  }

  // ---- GEMM1-v: v2_c = msgV[.,c,192] @ Wl1frag(w)   (K=192, 3 comps)
  f32x4 v2[3];
#pragma unroll
  for (int c = 0; c < 3; c++) v2[c] = (f32x4){0.f, 0.f, 0.f, 0.f};
#pragma unroll
  for (int ks = 0; ks < 6; ks++) {
    bf16x8 Bh = *(const bf16x8*)(bwH + (size_t)(FW1 + ks * 4 + w) * 512 +
                                 (size_t)l * 8);
    bf16x8 Bl = *(const bf16x8*)(bwL + (size_t)(FW1 + ks * 4 + w) * 512 +
                                 (size_t)l * 8);
#pragma unroll
    for (int c = 0; c < 3; c++) {
      size_t o = (size_t)rowA * 576 + c * 192 + ks * 32 + q * 8;
      bf16x8 Ah = *(const bf16x8*)(msgVh + o);
      bf16x8 Al = *(const bf16x8*)(msgVl + o);
      v2[c] = __builtin_amdgcn_mfma_f32_16x16x32_bf16(Ah, Bh, v2[c], 0, 0, 0);
      v2[c] = __builtin_amdgcn_mfma_f32_16x16x32_bf16(Al, Bh, v2[c], 0, 0, 0);
      v2[c] = __builtin_amdgcn_mfma_f32_16x16x32_bf16(Ah, Bl, v2[c], 0, 0, 0);
    }
  }

  // ---- elementwise species mix (C-frag layout: row=q*4+r, col=w*16+m)
  float os[4], ov0[4], ov1[4], ov2[4];
#pragma unroll
  for (int r = 0; r < 4; r++) {
    int node = n0 + q * 4 + r;
    int nc = node > nN - 1 ? nN - 1 : node;
    int a = an[nc];
    int ch = w * 16 + m;
    float s2v = s2[r];
    float va = v2[0][r], vb = v2[1][r], vc = v2[2][r];
    float vv = va * va + vb * vb + vc * vc;
    float w01  = cw[CW_S01 + a * 64 + ch];
    float w02a = cw[CW_S02 + a * 128 + ch];
    float w02b = cw[CW_S02 + a * 128 + 64 + ch];
    float w03a = cw[CW_S03 + a * 128 + ch];
    float w03b = cw[CW_S03 + a * 128 + 64 + ch];
    float w11  = cw[CW_S11 + a * 64 + ch];
    float w12  = cw[CW_S12 + a * 64 + ch];
    float w13a = cw[CW_S13 + a * 128 + ch];
    float w13b = cw[CW_S13 + a * 128 + 64 + ch];
    float s2sq = s2v * s2v;
    float vvs = vv * INV_SQRT3;
    os[r] = w01 * s2v + w02a * s2sq + w02b * vvs + w03a * s2sq * s2v +
            w03b * s2v * vvs;
    float coef = w11 + w12 * s2v + w13a * s2sq + w13b * vvs;
    ov0[r] = coef * va;
    ov1[r] = coef * vb;
    ov2[r] = coef * vc;
  }

  // ---- GEMM2 x4 through u16 hi/lo LDS transpose
#define POST2_G2(SRC, FB, STORE_S, COMP)                                       \
  {                                                                            \
    __syncthreads();                                                           \
    _Pragma("unroll")                                                          \
    for (int r = 0; r < 4; r++) {                                              \
      float x = SRC[r];                                                        \
      u16 h = f2b(x);                                                          \
      Thi[q * 4 + r][w * 16 + m] = h;                                          \
      Tlo[q * 4 + r][w * 16 + m] = f2b(x - b2f(h));                            \
    }                                                                          \
    __syncthreads();                                                           \
    f32x4 d = (f32x4){0.f, 0.f, 0.f, 0.f};                                     \
    _Pragma("unroll")                                                          \
    for (int ks = 0; ks < 2; ks++) {                                           \
      bf16x8 Bh = *(const bf16x8*)(bwH + (size_t)(FB + ks * 4 + w) * 512 +     \
                                   (size_t)l * 8);                             \
      bf16x8 Bl = *(const bf16x8*)(bwL + (size_t)(FB + ks * 4 + w) * 512 +     \
                                   (size_t)l * 8);                             \
      bf16x8 Ah = *(const bf16x8*)(&Thi[m][ks * 32 + q * 8]);                  \
      bf16x8 Al = *(const bf16x8*)(&Tlo[m][ks * 32 + q * 8]);                  \
      d = __builtin_amdgcn_mfma_f32_16x16x32_bf16(Ah, Bh, d, 0, 0, 0);         \
      d = __builtin_amdgcn_mfma_f32_16x16x32_bf16(Al, Bh, d, 0, 0, 0);         \
      d = __builtin_amdgcn_mfma_f32_16x16x32_bf16(Ah, Bl, d, 0, 0, 0);         \
    }                                                                          \
    _Pragma("unroll")                                                          \
    for (int r = 0; r < 4; r++) {                                              \
      int node = n0 + q * 4 + r;                                               \
      if (node < nN) {                                                         \
        int ch = w * 16 + m;                                                   \
        size_t basep = (size_t)node * 256;                                     \
        size_t oidx = STORE_S ? (basep + ch) : (basep + 64 + ch * 3 + COMP);   \
        if (f32) ((float*)out)[oidx] = d[r];                                   \
        else ((u16*)out)[oidx] = f2b(d[r]);                                    \
      }                                                                        \
    }                                                                          \
  }

  POST2_G2(os, FP0, 1, 0)
  POST2_G2(ov0, FP1, 0, 0)
  POST2_G2(ov1, FP1, 0, 1)
  POST2_G2(ov2, FP1, 0, 2)
#undef POST2_G2
}

extern "C" void kernel_launch(void* const* d_in, const int* in_sizes, int n_in,
                              void* d_out, int out_size, void* d_ws,
                              size_t ws_size, hipStream_t stream) {
  const void* nf = d_in[0];
  const void* ef = d_in[1];
  const void* ea = d_in[2];
  const int* ie = (const int*)d_in[3];
  const int* je = (const int*)d_in[4];
  const int* an = (const int*)d_in[5];
  int nN = in_sizes[0] / 256;   // 20000
  int nE = in_sizes[3];         // 320000

  size_t intCnt = (size_t)3 * nN + 1 + nE;     // deg, offs, cursor, iSlot
  intCnt = (intCnt + 3) & ~(size_t)3;
  int* deg    = (int*)d_ws;
  int* offs   = deg + nN;
  int* cursor = offs + nN + 1;
  int* iSlot  = cursor + nN;
  float* cw   = (float*)d_ws + intCnt;
  float* sup  = cw + CW_TOTAL;
  float* vup  = sup + (size_t)nN * 64;
  int* flag   = (int*)(vup + (size_t)nN * 192);

  size_t msgByte = (size_t)((char*)(flag + 1) - (char*)d_ws);
  msgByte = (msgByte + 15) & ~(size_t)15;
  u16* msgSh = (u16*)((char*)d_ws + msgByte);
  u16* msgSl = msgSh + (size_t)nN * 128;
  u16* msgVh = msgSl + (size_t)nN * 128;
  u16* msgVl = msgVh + (size_t)nN * 576;

  size_t eaByte = msgByte + (size_t)nN * 1408 * 2;
  eaByte = (eaByte + 15) & ~(size_t)15;
  float4* eaSlot = (float4*)((char*)d_ws + eaByte);
  float4* efSlot = eaSlot + nE;                 // nE float4 x2 for ef
  size_t bwByte = eaByte + (size_t)nE * 16 + (size_t)nE * 32;
  u16* bwH = (u16*)((char*)d_ws + bwByte);
  u16* bwL = bwH + (size_t)NFRAG * 512;
  size_t tpwByte = bwByte + (size_t)NFRAG * 512 * 2 * 2;
  tpwByte = (tpwByte + 15) & ~(size_t)15;
  u16* tpw = (u16*)((char*)d_ws + tpwByte);
  size_t capE = (ws_size > tpwByte) ? (ws_size - tpwByte) / 640 : 0;

  // G policy: smallest g whose worst-case per-group slot count fits tpw
  // workspace (G=1 preferred).
  int G = 64;
  int nodesPer = (nN + 63) / 64;
  for (int g = 1; g <= 64; g++) {
    int npg = (nN + g - 1) / g;
    size_t worst = (size_t)npg * nE / nN + 6000;
    if (worst <= capE) { G = g; nodesPer = npg; break; }
  }
  int capEff = (int)((size_t)nodesPer * nE / nN + 6000);
  if ((size_t)capEff > capE) capEff = (int)capE;

  k_detect<<<1, 256, 0, stream>>>(nf, flag);
  hipMemsetAsync(deg, 0, (size_t)nN * sizeof(int), stream);

  WPtrs wp;
  const int widx[16] = {6, 7, 8, 9, 10, 11, 12, 13, 20, 21,
                        14, 15, 16, 17, 18, 19};
  for (int i = 0; i < 16; i++) wp.p[i] = d_in[widx[i]];

  int histNB = (nE + 255) / 256;
  int nb0 = 513 + histNB;
  int nupNB = (nN + 3) / 4;
  k_front<<<nb0 + nupNB, 256, 0, stream>>>(wp, cw, bwH, bwL, je, deg, nf,
                                           sup, vup, nN, nE, nb0, flag);
  k_scan<<<1, 256, 0, stream>>>(deg, offs, cursor, nN);
  k_scatter2<<<(nE + 255) / 256, 256, 0, stream>>>(je, ie, ea, ef, cursor,
                                                   iSlot, eaSlot, efSlot, nE,
                                                   flag);

  for (int g = 0; g < G; g++) {
    int gn0 = g * nodesPer;
    if (gn0 >= nN) break;
    int gn1 = gn0 + nodesPer; if (gn1 > nN) gn1 = nN;
    int mlpBlocks = (capEff + 191) / 192;
    k_mlp4<<<mlpBlocks, 192, 0, stream>>>(efSlot, offs, bwH, bwL, tpw,
                                          gn0, gn1, capEff);
    int gBlocks = (gn1 - gn0 + 3) / 4;
    k_gather6<<<gBlocks, 256, 0, stream>>>(iSlot, eaSlot, offs, sup, vup,
                                           tpw, msgSh, msgSl, msgVh, msgVl,
                                           gn0, gn1, capEff);
  }
  int postNB = (nN + 15) / 16;
  k_post2<<<postNB, 256, 0, stream>>>(msgSh, msgSl, msgVh, msgVl, an, cw,
                                      bwH, bwL, d_out, nN, flag);
}